// Round 5
// baseline (479.677 us; speedup 1.0000x reference)
//
#include <hip/hip_runtime.h>

constexpr int Bn  = 1024;
constexpr int Tn  = 8192;
constexpr int Wn  = 2048;   // NUM_WORDS
constexpr int TPB = 512;
constexpr int BPR = 4;              // blocks per row
constexpr int SEG = Tn / BPR;       // 2048 = TPB*4 elements per block

// Per-position rule evaluation (matches the vectorized reference exactly):
//   INIT_TOKENS  = {94,122,100,92,43,27} -> INIT_DURS {2,3,2,2,5,5}
//   RATIO_TOKENS = {44,28,29,27,121,43}
__device__ __forceinline__ void rule_eval(float dp, float dpn, int tok, bool valid_next,
                                          float& g1, float& g2, float& sa) {
  float expected;
  bool in_init = true;
  switch (tok) {
    case 94:  expected = 2.f; break;
    case 122: expected = 3.f; break;
    case 100: expected = 2.f; break;
    case 92:  expected = 2.f; break;
    case 43:  expected = 5.f; break;
    case 27:  expected = 5.f; break;
    default:  expected = 0.f; in_init = false; break;
  }
  float t1 = dp - expected;
  bool fire1 = in_init && (t1 > 0.f);
  g1 = fire1 ? t1 : 0.f;
  bool in_ratio = (tok == 44) | (tok == 28) | (tok == 29) |
                  (tok == 27) | (tok == 121) | (tok == 43);
  bool fire2 = in_ratio && valid_next && (3.f * dp > dpn);
  g2 = fire2 ? (dp - dpn * (1.f / 3.f)) : 0.f;
  sa = fire2 ? g2 : (fire1 ? g1 : 0.f);
}

__device__ __forceinline__ float wave_reduce(float v) {
  #pragma unroll
  for (int o = 32; o > 0; o >>= 1) v += __shfl_down(v, o, 64);
  return v;
}

// (512,8): cap VGPR at 64 -> full residency; MLP comes from TLP (one load phase/wave).
__global__ __launch_bounds__(TPB, 8) void loss_kernel(
    const float* __restrict__ dur_pred, const float* __restrict__ dur_gt,
    const int* __restrict__ ph2word, const int* __restrict__ txt,
    double* __restrict__ acc, unsigned* __restrict__ bcount,
    float* __restrict__ rowp, float* __restrict__ rowg,
    unsigned* __restrict__ rowcnt, float* __restrict__ out)
{
  __shared__ float wp[Wn];
  __shared__ float wg[Wn];
  __shared__ float sacc[5];   // pdur_s, rules_s, sp, sg, wd_s
  __shared__ int   smeta[3];  // [0]=lo  [1]=pw_next  [2]=pw_lastm1

  const int row = blockIdx.x >> 2;      // BPR == 4
  const int sub = blockIdx.x & 3;
  const int s = sub * SEG;
  const int e = s + SEG;
  const size_t roff = (size_t)row * Tn;
  const float* __restrict__ dpr = dur_pred + roff;
  const float* __restrict__ dgr = dur_gt + roff;
  const int*   __restrict__ pwr = ph2word + roff;
  const int*   __restrict__ tkr = txt + roff;

  const int tid  = threadIdx.x;
  const int lane = tid & 63;
  const bool is63 = (lane == 63);
  const int base = s + tid * 4;         // row-local position of this thread's 4 elems

  // ---- single load phase: everything this thread ever reads, issued up front ----
  float4 dp4 = *reinterpret_cast<const float4*>(dpr + base);
  float4 dg4 = *reinterpret_cast<const float4*>(dgr + base);
  int4   pw4 = *reinterpret_cast<const int4*>(pwr + base);
  int4   tk4 = *reinterpret_cast<const int4*>(tkr + base);

  // cross-wave neighbor data for j=3 (only lane 63 of each wave uses it)
  float nb_dp = 0.f, nb_dp1 = 0.f; int nb_tk = -1;
  if (is63) {
    const int p = base + 4;             // <= e; == Tn only for the row's last thread
    if (p < Tn) { nb_dp = dpr[p]; nb_dp1 = dpr[p + 1]; nb_tk = tkr[p]; }
  }

  // block word-range metadata (sorted keys): lo by thread 0, pw_lastm1 by thread 511
  if (tid == 0) {
    int lo;
    if (s == 0) lo = 1;                 // word 0 is dropped by the reference
    else {
      const int pw_prev = pwr[s - 1];
      lo = (pw_prev == pw4.x) ? pw4.x + 1 : pw4.x;
      if (lo < 1) lo = 1;
    }
    smeta[0] = lo;
    smeta[1] = (e < Tn) ? pwr[e] : -1;  // next block's first word (or -1)
  }
  if (tid == TPB - 1) smeta[2] = pw4.w; // this block's last word

  // zero LDS word accumulators (Wn/4 == TPB: one float4 per thread per array)
  {
    const float4 z = {0.f, 0.f, 0.f, 0.f};
    *reinterpret_cast<float4*>(&wp[tid * 4]) = z;
    *reinterpret_cast<float4*>(&wg[tid * 4]) = z;
  }
  if (tid < 5) sacc[tid] = 0.f;
  __syncthreads();

  // ---- compute phase ----
  float g1v[4], g2v[4], sav[4];
  rule_eval(dp4.x, dp4.y, tk4.x, true, g1v[0], g2v[0], sav[0]);
  rule_eval(dp4.y, dp4.z, tk4.y, true, g1v[1], g2v[1], sav[1]);
  rule_eval(dp4.z, dp4.w, tk4.z, true, g1v[2], g2v[2], sav[2]);
  float gg0 = g1v[0] + g2v[0];

  // neighbor for j=3: thread t+1's {dp4.x, gg0} via shuffle; lane63 from its loads
  float dpn3 = __shfl_down(dp4.x, 1, 64);
  float ggn  = __shfl_down(gg0,  1, 64);
  {
    float ng1, ng2, nsa_;
    rule_eval(nb_dp, nb_dp1, nb_tk, base + 4 < Tn - 1, ng1, ng2, nsa_);
    dpn3 = is63 ? nb_dp : dpn3;
    ggn  = is63 ? (ng1 + ng2) : ggn;
  }
  rule_eval(dp4.w, dpn3, tk4.w, base + 3 < Tn - 1, g1v[3], g2v[3], sav[3]);

  float dpx[4] = {dp4.x, dp4.y, dp4.z, dp4.w};
  float dgl[4] = {dg4.x, dg4.y, dg4.z, dg4.w};
  float addv[4] = {g1v[1] + g2v[1], g1v[2] + g2v[2], g1v[3] + g2v[3],
                   (base + 3 < Tn - 1) ? ggn : 0.f};

  float pdur_s = 0.f, rules_s = 0.f, sp = 0.f, sg = 0.f;
  #pragma unroll
  for (int j = 0; j < 4; ++j) {
    float dp = dpx[j];
    float dr = dp - sav[j] + addv[j];        // dur_rules[i]
    float lp = __logf(dp + 1.f);
    float dlr = lp - __logf(dr + 1.f);
    rules_s += dlr * dlr;
    float dlg = lp - __logf(dgl[j] + 1.f);
    pdur_s += dlg * dlg;
    sp += fmaxf(dp, 0.f);
    sg += dgl[j];
  }

  // word segment sums: sorted keys -> run-compress, LDS atomics
  {
    int pwl[4] = {pw4.x, pw4.y, pw4.z, pw4.w};
    int curw = pwl[0];
    float ap = 0.f, ag = 0.f;
    #pragma unroll
    for (int j = 0; j < 4; ++j) {
      if (pwl[j] != curw) {
        atomicAdd(&wp[curw], ap);
        atomicAdd(&wg[curw], ag);
        curw = pwl[j]; ap = 0.f; ag = 0.f;
      }
      ap += fmaxf(dpx[j], 0.f);
      ag += dgl[j];
    }
    atomicAdd(&wp[curw], ap);
    atomicAdd(&wg[curw], ag);
  }

  __syncthreads();

  const int lo        = smeta[0];
  const int pw_next   = smeta[1];
  const int pw_lastm1 = smeta[2];
  const int hi = (e == Tn) ? Wn : ((pw_lastm1 == pw_next) ? pw_next + 1 : pw_next);

  // boundary run completion: if our last word's run continues past e and we own it,
  // wave 0 scans forward in global memory until the word changes.
  if (tid < 64) {
    const int w_end = pw_lastm1;
    const bool doscan = (e < Tn) && (pw_next == w_end) && (w_end >= lo);
    if (doscan) {
      float ap = 0.f, ag = 0.f;
      int p = e + lane;
      for (;;) {
        bool in = (p < Tn) && (pwr[p] == w_end);
        if (in) { float d = dpr[p]; ap += fmaxf(d, 0.f); ag += dgr[p]; }
        if (__ballot(in) != ~0ull) break;   // run ended inside this 64-window
        p += 64;
      }
      ap = wave_reduce(ap);
      ag = wave_reduce(ag);
      if (lane == 0) { atomicAdd(&wp[w_end], ap); atomicAdd(&wg[w_end], ag); }
    }
  }
  __syncthreads();

  // word-duration loss over this block's owned words [lo, hi)
  float wd_s = 0.f;
  for (int w = lo + tid; w < hi; w += TPB) {
    float d = __logf(wp[w] + 1.f) - __logf(wg[w] + 1.f);
    wd_s += d * d;
  }

  pdur_s  = wave_reduce(pdur_s);
  rules_s = wave_reduce(rules_s);
  sp      = wave_reduce(sp);
  sg      = wave_reduce(sg);
  wd_s    = wave_reduce(wd_s);
  if (lane == 0) {
    atomicAdd(&sacc[0], pdur_s);
    atomicAdd(&sacc[1], rules_s);
    atomicAdd(&sacc[2], sp);
    atomicAdd(&sacc[3], sg);
    atomicAdd(&sacc[4], wd_s);
  }
  __syncthreads();

  if (tid == 0) {
    double contrib = 0.6 * (double)sacc[0] / ((double)Bn * (double)Tn)
                   + 0.3 * (double)sacc[1] / ((double)Bn * (double)Tn)
                   + 0.3 * (double)sacc[4] / ((double)Bn * (double)(Wn - 1));
    atomicAdd(acc, contrib);
    // device-scope atomic accumulate; the 4th arriving block folds in the sdur term.
    atomicAdd(&rowp[row], sacc[2]);
    atomicAdd(&rowg[row], sacc[3]);
    __threadfence();
    unsigned rp = atomicAdd(&rowcnt[row], 1u);
    if (rp == (unsigned)(BPR - 1)) {   // last block of this row
      // read back through device-scope atomics (coherent; volatile loads could
      // be served stale by L1 per XCD-coherence rules)
      float spr = atomicAdd(&rowp[row], 0.0f);
      float sgr = atomicAdd(&rowg[row], 0.0f);
      float ds = __logf(spr + 1.f) - __logf(sgr + 1.f);
      atomicAdd(acc, 0.1 * (double)(ds * ds) / (double)Bn);
    }
    __threadfence();
    unsigned prev = atomicAdd(bcount, 1u);
    if (prev == (unsigned)(gridDim.x - 1)) {  // last block overall: write output
      double accv = atomicAdd(acc, 0.0);      // coherent read-back
      out[0] = (float)accv;
    }
  }
}

extern "C" void kernel_launch(void* const* d_in, const int* in_sizes, int n_in,
                              void* d_out, int out_size, void* d_ws, size_t ws_size,
                              hipStream_t stream) {
  const float* dur_pred = (const float*)d_in[0];
  const float* dur_gt   = (const float*)d_in[1];
  const int*   ph2word  = (const int*)d_in[2];
  const int*   txt      = (const int*)d_in[3];

  // workspace layout: [double acc][uint bcount][pad][rowp Bn][rowg Bn][rowcnt Bn]
  double*   acc    = (double*)d_ws;
  unsigned* bcount = (unsigned*)((char*)d_ws + 8);
  float*    rowp   = (float*)((char*)d_ws + 16);
  float*    rowg   = rowp + Bn;
  unsigned* rowcnt = (unsigned*)(rowg + Bn);
  const size_t ws_used = 16 + (size_t)Bn * 12;

  hipMemsetAsync(d_ws, 0, ws_used, stream);
  loss_kernel<<<Bn * BPR, TPB, 0, stream>>>(dur_pred, dur_gt, ph2word, txt,
                                            acc, bcount, rowp, rowg, rowcnt,
                                            (float*)d_out);
}

// Round 6
// 183.028 us; speedup vs baseline: 2.6208x; 2.6208x over previous
//
#include <hip/hip_runtime.h>

constexpr int Bn  = 1024;
constexpr int Tn  = 8192;
constexpr int Wn  = 2048;   // NUM_WORDS
constexpr int TPB = 512;
constexpr int BPR = 4;              // blocks per row
constexpr int SEG = Tn / BPR;       // 2048 = TPB*4 elements per block

// Per-position rule evaluation (matches the vectorized reference exactly):
//   INIT_TOKENS  = {94,122,100,92,43,27} -> INIT_DURS {2,3,2,2,5,5}
//   RATIO_TOKENS = {44,28,29,27,121,43}
__device__ __forceinline__ void rule_eval(float dp, float dpn, int tok, bool valid_next,
                                          float& g1, float& g2, float& sa) {
  float expected;
  bool in_init = true;
  switch (tok) {
    case 94:  expected = 2.f; break;
    case 122: expected = 3.f; break;
    case 100: expected = 2.f; break;
    case 92:  expected = 2.f; break;
    case 43:  expected = 5.f; break;
    case 27:  expected = 5.f; break;
    default:  expected = 0.f; in_init = false; break;
  }
  float t1 = dp - expected;
  bool fire1 = in_init && (t1 > 0.f);
  g1 = fire1 ? t1 : 0.f;
  bool in_ratio = (tok == 44) | (tok == 28) | (tok == 29) |
                  (tok == 27) | (tok == 121) | (tok == 43);
  bool fire2 = in_ratio && valid_next && (3.f * dp > dpn);
  g2 = fire2 ? (dp - dpn * (1.f / 3.f)) : 0.f;
  sa = fire2 ? g2 : (fire1 ? g1 : 0.f);
}

__device__ __forceinline__ float wave_reduce(float v) {
  #pragma unroll
  for (int o = 32; o > 0; o >>= 1) v += __shfl_down(v, o, 64);
  return v;
}

// (512,8): 4 blocks/CU, 32 waves/CU residency. ZERO global atomics anywhere:
// each block writes its partial sums to a distinct slot; finalize_kernel reduces.
__global__ __launch_bounds__(TPB, 8) void loss_kernel(
    const float* __restrict__ dur_pred, const float* __restrict__ dur_gt,
    const int* __restrict__ ph2word, const int* __restrict__ txt,
    float4* __restrict__ partials)
{
  __shared__ float wp[Wn];
  __shared__ float wg[Wn];
  __shared__ float sacc[5];   // pdur_s, rules_s, sp, sg, wd_s
  __shared__ int   smeta[3];  // [0]=lo  [1]=pw_next  [2]=pw_lastm1

  const int row = blockIdx.x >> 2;      // BPR == 4
  const int sub = blockIdx.x & 3;
  const int s = sub * SEG;
  const int e = s + SEG;
  const size_t roff = (size_t)row * Tn;
  const float* __restrict__ dpr = dur_pred + roff;
  const float* __restrict__ dgr = dur_gt + roff;
  const int*   __restrict__ pwr = ph2word + roff;
  const int*   __restrict__ tkr = txt + roff;

  const int tid  = threadIdx.x;
  const int lane = tid & 63;
  const bool is63 = (lane == 63);
  const int base = s + tid * 4;         // row-local position of this thread's 4 elems

  // ---- single load phase: everything this thread ever reads, issued up front ----
  float4 dp4 = *reinterpret_cast<const float4*>(dpr + base);
  float4 dg4 = *reinterpret_cast<const float4*>(dgr + base);
  int4   pw4 = *reinterpret_cast<const int4*>(pwr + base);
  int4   tk4 = *reinterpret_cast<const int4*>(tkr + base);

  // cross-wave neighbor data for j=3 (only lane 63 of each wave uses it)
  float nb_dp = 0.f, nb_dp1 = 0.f; int nb_tk = -1;
  if (is63) {
    const int p = base + 4;             // <= e; == Tn only for the row's last thread
    if (p < Tn) { nb_dp = dpr[p]; nb_dp1 = dpr[p + 1]; nb_tk = tkr[p]; }
  }

  // block word-range metadata (sorted keys): lo by thread 0, pw_lastm1 by thread 511
  if (tid == 0) {
    int lo;
    if (s == 0) lo = 1;                 // word 0 is dropped by the reference
    else {
      const int pw_prev = pwr[s - 1];
      lo = (pw_prev == pw4.x) ? pw4.x + 1 : pw4.x;
      if (lo < 1) lo = 1;
    }
    smeta[0] = lo;
    smeta[1] = (e < Tn) ? pwr[e] : -1;  // next block's first word (or -1)
  }
  if (tid == TPB - 1) smeta[2] = pw4.w; // this block's last word

  // zero LDS word accumulators (Wn/4 == TPB: one float4 store per thread per array)
  {
    const float4 z = {0.f, 0.f, 0.f, 0.f};
    *reinterpret_cast<float4*>(&wp[tid * 4]) = z;
    *reinterpret_cast<float4*>(&wg[tid * 4]) = z;
  }
  if (tid < 5) sacc[tid] = 0.f;
  __syncthreads();

  // ---- compute phase ----
  float g1v[4], g2v[4], sav[4];
  rule_eval(dp4.x, dp4.y, tk4.x, true, g1v[0], g2v[0], sav[0]);
  rule_eval(dp4.y, dp4.z, tk4.y, true, g1v[1], g2v[1], sav[1]);
  rule_eval(dp4.z, dp4.w, tk4.z, true, g1v[2], g2v[2], sav[2]);
  float gg0 = g1v[0] + g2v[0];

  // neighbor for j=3: thread t+1's {dp4.x, gg0} via shuffle; lane63 from its loads
  float dpn3 = __shfl_down(dp4.x, 1, 64);
  float ggn  = __shfl_down(gg0,  1, 64);
  {
    float ng1, ng2, nsa_;
    rule_eval(nb_dp, nb_dp1, nb_tk, base + 4 < Tn - 1, ng1, ng2, nsa_);
    dpn3 = is63 ? nb_dp : dpn3;
    ggn  = is63 ? (ng1 + ng2) : ggn;
  }
  rule_eval(dp4.w, dpn3, tk4.w, base + 3 < Tn - 1, g1v[3], g2v[3], sav[3]);

  float dpx[4] = {dp4.x, dp4.y, dp4.z, dp4.w};
  float dgl[4] = {dg4.x, dg4.y, dg4.z, dg4.w};
  float addv[4] = {g1v[1] + g2v[1], g1v[2] + g2v[2], g1v[3] + g2v[3],
                   (base + 3 < Tn - 1) ? ggn : 0.f};

  float pdur_s = 0.f, rules_s = 0.f, sp = 0.f, sg = 0.f;
  #pragma unroll
  for (int j = 0; j < 4; ++j) {
    float dp = dpx[j];
    float dr = dp - sav[j] + addv[j];        // dur_rules[i]
    float lp = __logf(dp + 1.f);
    float dlr = lp - __logf(dr + 1.f);
    rules_s += dlr * dlr;
    float dlg = lp - __logf(dgl[j] + 1.f);
    pdur_s += dlg * dlg;
    sp += fmaxf(dp, 0.f);
    sg += dgl[j];
  }

  // word segment sums: sorted keys -> run-compress, LDS atomics
  {
    int pwl[4] = {pw4.x, pw4.y, pw4.z, pw4.w};
    int curw = pwl[0];
    float ap = 0.f, ag = 0.f;
    #pragma unroll
    for (int j = 0; j < 4; ++j) {
      if (pwl[j] != curw) {
        atomicAdd(&wp[curw], ap);
        atomicAdd(&wg[curw], ag);
        curw = pwl[j]; ap = 0.f; ag = 0.f;
      }
      ap += fmaxf(dpx[j], 0.f);
      ag += dgl[j];
    }
    atomicAdd(&wp[curw], ap);
    atomicAdd(&wg[curw], ag);
  }

  __syncthreads();

  const int lo        = smeta[0];
  const int pw_next   = smeta[1];
  const int pw_lastm1 = smeta[2];
  const int hi = (e == Tn) ? Wn : ((pw_lastm1 == pw_next) ? pw_next + 1 : pw_next);

  // boundary run completion: if our last word's run continues past e and we own it,
  // wave 0 scans forward in global memory until the word changes.
  if (tid < 64) {
    const int w_end = pw_lastm1;
    const bool doscan = (e < Tn) && (pw_next == w_end) && (w_end >= lo);
    if (doscan) {
      float ap = 0.f, ag = 0.f;
      int p = e + lane;
      for (;;) {
        bool in = (p < Tn) && (pwr[p] == w_end);
        if (in) { float d = dpr[p]; ap += fmaxf(d, 0.f); ag += dgr[p]; }
        if (__ballot(in) != ~0ull) break;   // run ended inside this 64-window
        p += 64;
      }
      ap = wave_reduce(ap);
      ag = wave_reduce(ag);
      if (lane == 0) { atomicAdd(&wp[w_end], ap); atomicAdd(&wg[w_end], ag); }
    }
  }
  __syncthreads();

  // word-duration loss over this block's owned words [lo, hi)
  float wd_s = 0.f;
  for (int w = lo + tid; w < hi; w += TPB) {
    float d = __logf(wp[w] + 1.f) - __logf(wg[w] + 1.f);
    wd_s += d * d;
  }

  pdur_s  = wave_reduce(pdur_s);
  rules_s = wave_reduce(rules_s);
  sp      = wave_reduce(sp);
  sg      = wave_reduce(sg);
  wd_s    = wave_reduce(wd_s);
  if (lane == 0) {
    atomicAdd(&sacc[0], pdur_s);
    atomicAdd(&sacc[1], rules_s);
    atomicAdd(&sacc[2], sp);
    atomicAdd(&sacc[3], sg);
    atomicAdd(&sacc[4], wd_s);
  }
  __syncthreads();

  // epilogue: plain stores to a distinct 32 B slot per block. No global atomics.
  if (tid == 0) {
    float4 a; a.x = sacc[0]; a.y = sacc[1]; a.z = sacc[4]; a.w = sacc[2];
    float4 b; b.x = sacc[3]; b.y = 0.f; b.z = 0.f; b.w = 0.f;
    partials[(size_t)blockIdx.x * 2]     = a;   // {pdur, rules, wd, sp}
    partials[(size_t)blockIdx.x * 2 + 1] = b;   // {sg, -, -, -}
  }
}

// One block: thread r folds row r's BPR partials, computes the row's ds^2 term,
// then block-reduce in double. Kernel boundary guarantees partials visibility.
__global__ __launch_bounds__(1024) void finalize_kernel(
    const float4* __restrict__ partials, float* __restrict__ out)
{
  __shared__ double wsum[16];
  const int r = threadIdx.x;            // one row per thread, Bn == 1024 == blockDim
  double pd = 0.0, rl = 0.0, wd = 0.0;
  float sp = 0.f, sg = 0.f;
  #pragma unroll
  for (int j = 0; j < BPR; ++j) {
    const size_t idx = ((size_t)r * BPR + j) * 2;
    float4 a = partials[idx];
    float4 b = partials[idx + 1];
    pd += (double)a.x; rl += (double)a.y; wd += (double)a.z;
    sp += a.w; sg += b.x;
  }
  float ds = __logf(sp + 1.f) - __logf(sg + 1.f);
  double contrib = 0.6 * pd / ((double)Bn * (double)Tn)
                 + 0.3 * rl / ((double)Bn * (double)Tn)
                 + 0.3 * wd / ((double)Bn * (double)(Wn - 1))
                 + 0.1 * (double)(ds * ds) / (double)Bn;
  #pragma unroll
  for (int o = 32; o > 0; o >>= 1) contrib += __shfl_down(contrib, o, 64);
  if ((threadIdx.x & 63) == 0) wsum[threadIdx.x >> 6] = contrib;
  __syncthreads();
  if (threadIdx.x == 0) {
    double t = 0.0;
    #pragma unroll
    for (int i = 0; i < 16; ++i) t += wsum[i];
    out[0] = (float)t;
  }
}

extern "C" void kernel_launch(void* const* d_in, const int* in_sizes, int n_in,
                              void* d_out, int out_size, void* d_ws, size_t ws_size,
                              hipStream_t stream) {
  const float* dur_pred = (const float*)d_in[0];
  const float* dur_gt   = (const float*)d_in[1];
  const int*   ph2word  = (const int*)d_in[2];
  const int*   txt      = (const int*)d_in[3];

  // workspace: 4096 blocks x 32 B partials = 128 KB, fully overwritten (no memset)
  float4* partials = (float4*)d_ws;

  loss_kernel<<<Bn * BPR, TPB, 0, stream>>>(dur_pred, dur_gt, ph2word, txt, partials);
  finalize_kernel<<<1, 1024, 0, stream>>>(partials, (float*)d_out);
}

// Round 7
// 181.124 us; speedup vs baseline: 2.6483x; 1.0105x over previous
//
#include <hip/hip_runtime.h>

constexpr int Bn  = 1024;
constexpr int Tn  = 8192;
constexpr int Wn  = 2048;   // NUM_WORDS
constexpr int TPB = 512;
constexpr int BPR = 4;              // blocks per row
constexpr int SEG = Tn / BPR;       // 2048 = TPB*4 elements per block

// Per-position rule evaluation (matches the vectorized reference exactly):
//   INIT_TOKENS  = {94,122,100,92,43,27} -> INIT_DURS {2,3,2,2,5,5}
//   RATIO_TOKENS = {44,28,29,27,121,43}
__device__ __forceinline__ void rule_eval(float dp, float dpn, int tok, bool valid_next,
                                          float& g1, float& g2, float& sa) {
  float expected;
  bool in_init = true;
  switch (tok) {
    case 94:  expected = 2.f; break;
    case 122: expected = 3.f; break;
    case 100: expected = 2.f; break;
    case 92:  expected = 2.f; break;
    case 43:  expected = 5.f; break;
    case 27:  expected = 5.f; break;
    default:  expected = 0.f; in_init = false; break;
  }
  float t1 = dp - expected;
  bool fire1 = in_init && (t1 > 0.f);
  g1 = fire1 ? t1 : 0.f;
  bool in_ratio = (tok == 44) | (tok == 28) | (tok == 29) |
                  (tok == 27) | (tok == 121) | (tok == 43);
  bool fire2 = in_ratio && valid_next && (3.f * dp > dpn);
  g2 = fire2 ? (dp - dpn * (1.f / 3.f)) : 0.f;
  sa = fire2 ? g2 : (fire1 ? g1 : 0.f);
}

__device__ __forceinline__ float wave_reduce(float v) {
  #pragma unroll
  for (int o = 32; o > 0; o >>= 1) v += __shfl_down(v, o, 64);
  return v;
}

// (512,8): full residency; no global atomics; no cross-block scan — boundary
// words are emitted as partial sums and merged in finalize_kernel.
__global__ __launch_bounds__(TPB, 8) void loss_kernel(
    const float* __restrict__ dur_pred, const float* __restrict__ dur_gt,
    const int* __restrict__ ph2word, const int* __restrict__ txt,
    float4* __restrict__ partials)
{
  __shared__ float wp[Wn];
  __shared__ float wg[Wn];
  __shared__ float sacc[5];   // pdur_s, rules_s, sp, sg, wd_s
  __shared__ int   smeta[2];  // [0]=wfirst  [1]=wlast

  const int row = blockIdx.x >> 2;      // BPR == 4
  const int sub = blockIdx.x & 3;
  const int s = sub * SEG;
  const size_t roff = (size_t)row * Tn;
  const float* __restrict__ dpr = dur_pred + roff;
  const float* __restrict__ dgr = dur_gt + roff;
  const int*   __restrict__ pwr = ph2word + roff;
  const int*   __restrict__ tkr = txt + roff;

  const int tid  = threadIdx.x;
  const int lane = tid & 63;
  const bool is63 = (lane == 63);
  const int base = s + tid * 4;         // row-local position of this thread's 4 elems

  // ---- single load phase: everything this thread ever reads, issued up front ----
  float4 dp4 = *reinterpret_cast<const float4*>(dpr + base);
  float4 dg4 = *reinterpret_cast<const float4*>(dgr + base);
  int4   pw4 = *reinterpret_cast<const int4*>(pwr + base);
  int4   tk4 = *reinterpret_cast<const int4*>(tkr + base);

  // cross-wave neighbor data for j=3 (only lane 63 of each wave uses it)
  float nb_dp = 0.f, nb_dp1 = 0.f; int nb_tk = -1;
  if (is63) {
    const int p = base + 4;             // <= e; == Tn only for the row's last thread
    if (p < Tn) { nb_dp = dpr[p]; nb_dp1 = dpr[p + 1]; nb_tk = tkr[p]; }
  }

  // block word range (sorted keys): wfirst by thread 0, wlast by thread 511
  if (tid == 0)       smeta[0] = pw4.x;
  if (tid == TPB - 1) smeta[1] = pw4.w;

  // zero LDS word accumulators (Wn/4 == TPB: one float4 store per thread per array)
  {
    const float4 z = {0.f, 0.f, 0.f, 0.f};
    *reinterpret_cast<float4*>(&wp[tid * 4]) = z;
    *reinterpret_cast<float4*>(&wg[tid * 4]) = z;
  }
  if (tid < 5) sacc[tid] = 0.f;
  __syncthreads();

  // ---- compute phase ----
  float g1v[4], g2v[4], sav[4];
  rule_eval(dp4.x, dp4.y, tk4.x, true, g1v[0], g2v[0], sav[0]);
  rule_eval(dp4.y, dp4.z, tk4.y, true, g1v[1], g2v[1], sav[1]);
  rule_eval(dp4.z, dp4.w, tk4.z, true, g1v[2], g2v[2], sav[2]);
  float gg0 = g1v[0] + g2v[0];

  // neighbor for j=3: thread t+1's {dp4.x, gg0} via shuffle; lane63 from its loads
  float dpn3 = __shfl_down(dp4.x, 1, 64);
  float ggn  = __shfl_down(gg0,  1, 64);
  {
    float ng1, ng2, nsa_;
    rule_eval(nb_dp, nb_dp1, nb_tk, base + 4 < Tn - 1, ng1, ng2, nsa_);
    dpn3 = is63 ? nb_dp : dpn3;
    ggn  = is63 ? (ng1 + ng2) : ggn;
  }
  rule_eval(dp4.w, dpn3, tk4.w, base + 3 < Tn - 1, g1v[3], g2v[3], sav[3]);

  float dpx[4] = {dp4.x, dp4.y, dp4.z, dp4.w};
  float dgl[4] = {dg4.x, dg4.y, dg4.z, dg4.w};
  float addv[4] = {g1v[1] + g2v[1], g1v[2] + g2v[2], g1v[3] + g2v[3],
                   (base + 3 < Tn - 1) ? ggn : 0.f};

  float pdur_s = 0.f, rules_s = 0.f, sp = 0.f, sg = 0.f;
  #pragma unroll
  for (int j = 0; j < 4; ++j) {
    float dp = dpx[j];
    float dr = dp - sav[j] + addv[j];        // dur_rules[i]
    float lp = __logf(dp + 1.f);
    float dlr = lp - __logf(dr + 1.f);
    rules_s += dlr * dlr;
    float dlg = lp - __logf(dgl[j] + 1.f);
    pdur_s += dlg * dlg;
    sp += fmaxf(dp, 0.f);
    sg += dgl[j];
  }

  // word segment sums: sorted keys -> run-compress, LDS atomics
  {
    int pwl[4] = {pw4.x, pw4.y, pw4.z, pw4.w};
    int curw = pwl[0];
    float ap = 0.f, ag = 0.f;
    #pragma unroll
    for (int j = 0; j < 4; ++j) {
      if (pwl[j] != curw) {
        atomicAdd(&wp[curw], ap);
        atomicAdd(&wg[curw], ag);
        curw = pwl[j]; ap = 0.f; ag = 0.f;
      }
      ap += fmaxf(dpx[j], 0.f);
      ag += dgl[j];
    }
    atomicAdd(&wp[curw], ap);
    atomicAdd(&wg[curw], ag);
  }

  __syncthreads();

  const int wf = smeta[0];
  const int wl = smeta[1];

  // word-duration loss over words strictly inside (wf, wl).
  // Sortedness guarantees those words' runs are fully contained in this block:
  // a run crossing the right edge would make its word == wl; crossing the left
  // edge would make it == wf.
  float wd_s = 0.f;
  for (int w = wf + 1 + tid; w < wl; w += TPB) {
    float d = __logf(wp[w] + 1.f) - __logf(wg[w] + 1.f);
    wd_s += d * d;
  }

  pdur_s  = wave_reduce(pdur_s);
  rules_s = wave_reduce(rules_s);
  sp      = wave_reduce(sp);
  sg      = wave_reduce(sg);
  wd_s    = wave_reduce(wd_s);
  if (lane == 0) {
    atomicAdd(&sacc[0], pdur_s);
    atomicAdd(&sacc[1], rules_s);
    atomicAdd(&sacc[2], sp);
    atomicAdd(&sacc[3], sg);
    atomicAdd(&sacc[4], wd_s);
  }
  __syncthreads();

  // epilogue: plain stores of {scalars, boundary-word partial sums}. No atomics.
  if (tid == 0) {
    float4 a, b, c;
    a.x = sacc[0]; a.y = sacc[1]; a.z = sacc[4]; a.w = sacc[2];
    b.x = sacc[3];
    if (wf != wl) { b.y = wp[wf]; b.z = wg[wf]; b.w = __int_as_float(wf); }
    else          { b.y = 0.f;    b.z = 0.f;    b.w = __int_as_float(-1); }
    c.x = wp[wl]; c.y = wg[wl]; c.z = __int_as_float(wl); c.w = 0.f;
    const size_t idx = (size_t)blockIdx.x * 3;
    partials[idx]     = a;   // {pdur, rules, wd_interior, sp}
    partials[idx + 1] = b;   // {sg, wf_p, wf_g, wf_id}
    partials[idx + 2] = c;   // {wl_p, wl_g, wl_id, -}
  }
}

// One block: thread r folds row r's BPR partials; boundary words arrive in
// non-decreasing id order (sorted keys), each spanning <=2 blocks -> run-merge.
__global__ __launch_bounds__(1024) void finalize_kernel(
    const float4* __restrict__ partials, float* __restrict__ out)
{
  __shared__ double wsum[16];
  const int r = threadIdx.x;            // one row per thread, Bn == 1024 == blockDim
  double pd = 0.0, rl = 0.0, wd = 0.0;
  float sp = 0.f, sg = 0.f;
  int curid = -1; float cp = 0.f, cg = 0.f;

  #pragma unroll
  for (int j = 0; j < BPR; ++j) {
    const size_t idx = ((size_t)r * BPR + j) * 3;
    float4 a = partials[idx];
    float4 b = partials[idx + 1];
    float4 c = partials[idx + 2];
    pd += (double)a.x; rl += (double)a.y; wd += (double)a.z;
    sp += a.w; sg += b.x;
    const int wfi = __float_as_int(b.w);
    const int wla = __float_as_int(c.z);
    if (wfi >= 0) {
      if (wfi != curid) {
        if (curid > 0) { float d = __logf(cp + 1.f) - __logf(cg + 1.f); wd += (double)(d * d); }
        curid = wfi; cp = 0.f; cg = 0.f;
      }
      cp += b.y; cg += b.z;
    }
    if (wla >= 0) {
      if (wla != curid) {
        if (curid > 0) { float d = __logf(cp + 1.f) - __logf(cg + 1.f); wd += (double)(d * d); }
        curid = wla; cp = 0.f; cg = 0.f;
      }
      cp += c.x; cg += c.y;
    }
  }
  if (curid > 0) { float d = __logf(cp + 1.f) - __logf(cg + 1.f); wd += (double)(d * d); }

  float ds = __logf(sp + 1.f) - __logf(sg + 1.f);
  double contrib = 0.6 * pd / ((double)Bn * (double)Tn)
                 + 0.3 * rl / ((double)Bn * (double)Tn)
                 + 0.3 * wd / ((double)Bn * (double)(Wn - 1))
                 + 0.1 * (double)(ds * ds) / (double)Bn;

  #pragma unroll
  for (int o = 32; o > 0; o >>= 1) contrib += __shfl_down(contrib, o, 64);
  if ((threadIdx.x & 63) == 0) wsum[threadIdx.x >> 6] = contrib;
  __syncthreads();
  if (threadIdx.x == 0) {
    double t = 0.0;
    #pragma unroll
    for (int i = 0; i < 16; ++i) t += wsum[i];
    out[0] = (float)t;
  }
}

extern "C" void kernel_launch(void* const* d_in, const int* in_sizes, int n_in,
                              void* d_out, int out_size, void* d_ws, size_t ws_size,
                              hipStream_t stream) {
  const float* dur_pred = (const float*)d_in[0];
  const float* dur_gt   = (const float*)d_in[1];
  const int*   ph2word  = (const int*)d_in[2];
  const int*   txt      = (const int*)d_in[3];

  // workspace: 4096 blocks x 48 B partials = 192 KB, fully overwritten (no memset)
  float4* partials = (float4*)d_ws;

  loss_kernel<<<Bn * BPR, TPB, 0, stream>>>(dur_pred, dur_gt, ph2word, txt, partials);
  finalize_kernel<<<1, 1024, 0, stream>>>(partials, (float*)d_out);
}

// Round 8
// 167.682 us; speedup vs baseline: 2.8606x; 1.0802x over previous
//
#include <hip/hip_runtime.h>

constexpr int Bn  = 1024;
constexpr int Tn  = 8192;
constexpr int Wn  = 2048;   // NUM_WORDS
constexpr int TPB = 256;
constexpr int NW  = TPB / 64;         // 4 waves per block
constexpr int SEG = TPB * 4;          // 1024 elements per block
constexpr int BPR = Tn / SEG;         // 8 blocks per row
// wd terms are folded into the per-block weighted scalar x with this factor so
// finalize can divide everything by Bn*Tn:  0.3*wd/(Bn*(Wn-1)) == WDC*wd/(Bn*Tn)
constexpr float WDC = 0.3f * (float)Tn / (float)(Wn - 1);

// Per-position rule evaluation (matches the vectorized reference exactly)
__device__ __forceinline__ void rule_eval(float dp, float dpn, int tok, bool valid_next,
                                          float& g1, float& g2, float& sa) {
  float expected;
  bool in_init = true;
  switch (tok) {
    case 94:  expected = 2.f; break;
    case 122: expected = 3.f; break;
    case 100: expected = 2.f; break;
    case 92:  expected = 2.f; break;
    case 43:  expected = 5.f; break;
    case 27:  expected = 5.f; break;
    default:  expected = 0.f; in_init = false; break;
  }
  float t1 = dp - expected;
  bool fire1 = in_init && (t1 > 0.f);
  g1 = fire1 ? t1 : 0.f;
  bool in_ratio = (tok == 44) | (tok == 28) | (tok == 29) |
                  (tok == 27) | (tok == 121) | (tok == 43);
  bool fire2 = in_ratio && valid_next && (3.f * dp > dpn);
  g2 = fire2 ? (dp - dpn * (1.f / 3.f)) : 0.f;
  sa = fire2 ? g2 : (fire1 ? g1 : 0.f);
}

__device__ __forceinline__ float wave_reduce(float v) {
  #pragma unroll
  for (int o = 32; o > 0; o >>= 1) v += __shfl_down(v, o, 64);
  return v;
}

// Word sums via in-register segmented reduction over sorted keys (no word LDS
// array, no LDS atomics, no zero/gather phases). 2 barriers total.
__global__ __launch_bounds__(TPB, 6) void loss_kernel(
    const float* __restrict__ dur_pred, const float* __restrict__ dur_gt,
    const int* __restrict__ ph2word, const int* __restrict__ txt,
    float4* __restrict__ partials)
{
  __shared__ int   hk[NW];                 // head key (k0 of lane 0) per wave
  __shared__ float ndp0[NW], ndp1[NW];     // lane0's dp4.x/.y  (rule neighbor handoff)
  __shared__ int   ntk[NW];                // lane0's tk4.x
  __shared__ int   twk[NW];                // wave tail-run key
  __shared__ float twp[NW], twg[NW];       // wave tail-run in-wave sums
  __shared__ int   wu_[NW];                // wave is entirely one run
  __shared__ float bnd[4];                 // {wf_p, wf_g, wl_p, wl_g}
  __shared__ int   smeta[2];               // {wf, wl}
  __shared__ float red[NW][3];             // {x, sp_wave, sg_wave}

  const int row = blockIdx.x / BPR;
  const int sub = blockIdx.x % BPR;
  const int s = sub * SEG;
  const size_t roff = (size_t)row * Tn;
  const float* __restrict__ dpr = dur_pred + roff;
  const float* __restrict__ dgr = dur_gt + roff;
  const int*   __restrict__ pwr = ph2word + roff;
  const int*   __restrict__ tkr = txt + roff;

  const int tid  = threadIdx.x;
  const int lane = tid & 63;
  const int wid  = tid >> 6;
  const bool is63 = (lane == 63);
  const int base = s + tid * 4;

  // ---- load phase ----
  float4 dp4 = *reinterpret_cast<const float4*>(dpr + base);
  float4 dg4 = *reinterpret_cast<const float4*>(dgr + base);
  int4   pw4 = *reinterpret_cast<const int4*>(pwr + base);
  int4   tk4 = *reinterpret_cast<const int4*>(tkr + base);

  // block-last thread: rule-neighbor comes from the next block's region
  float nb_dp = 0.f, nb_dp1 = 0.f; int nb_tk = -1;
  if (tid == TPB - 1) {
    const int p = base + 4;
    if (p < Tn) { nb_dp = dpr[p]; nb_dp1 = dpr[p + 1]; nb_tk = tkr[p]; }
  }

  const int k0 = pw4.x, k1 = pw4.y, k2 = pw4.z, k3 = pw4.w;
  const float p0 = fmaxf(dp4.x, 0.f), p1 = fmaxf(dp4.y, 0.f),
              p2 = fmaxf(dp4.z, 0.f), p3 = fmaxf(dp4.w, 0.f);
  const float g0 = dg4.x, g1_ = dg4.y, g2_ = dg4.z, g3_ = dg4.w;
  const float Sp = p0 + p1 + p2 + p3;
  const float Sg = g0 + g1_ + g2_ + g3_;

  // trailing-run partial sums within this thread (elements with key == k3)
  float t3p = p3, t3g = g3_;
  if (k2 == k3) { t3p += p2; t3g += g2_;
    if (k1 == k3) { t3p += p1; t3g += g1_;
      if (k0 == k3) { t3p += p0; t3g += g0; } } }

  // inclusive prefix scans of full-thread sums (also yields wave sp/sg at lane 63)
  float Pp = Sp, Pg = Sg;
  #pragma unroll
  for (int o = 1; o < 64; o <<= 1) {
    float tp = __shfl_up(Pp, o, 64);
    float tg = __shfl_up(Pg, o, 64);
    if (lane >= o) { Pp += tp; Pg += tg; }
  }

  // carry-in for the run containing my element 0
  const int nk0 = __shfl_down(k0, 1, 64);        // lanes 0..62 valid
  const bool uni = (k0 == k3);
  const bool cn  = uni && (k3 == nk0);           // continues into next lane
  const unsigned long long cmask = __ballot(cn);
  const unsigned long long below = (1ull << lane) - 1ull;
  const unsigned long long y = (~cmask) & below;
  const int L = y ? (64 - __clzll(y)) : 0;       // first lane of my carry range
  const int Lm1 = (L > 0) ? (L - 1) : 0;
  const float Ppm1 = __shfl_up(Pp, 1, 64);
  const float Pgm1 = __shfl_up(Pg, 1, 64);
  const float PpL = __shfl(Pp, Lm1, 64);
  const float PgL = __shfl(Pg, Lm1, 64);
  const int   k3L = __shfl(k3, Lm1, 64);
  const float tpL = __shfl(t3p, Lm1, 64);
  const float tgL = __shfl(t3g, Lm1, 64);
  float Cp = 0.f, Cg = 0.f;
  if (L < lane) {                                 // full uniform threads [L, lane-1]
    Cp = Ppm1 - (L > 0 ? PpL : 0.f);
    Cg = Pgm1 - (L > 0 ? PgL : 0.f);
  }
  if (L > 0 && k3L == k0) {                       // partial tail of thread L-1
    Cp += tpL; Cg += tgL;
  }
  const bool open = (y == 0);                     // run chains to wave start

  // rules j=0..2 (in-register neighbors)
  float g1v[4], g2v[4], sav[4];
  rule_eval(dp4.x, dp4.y, tk4.x, true, g1v[0], g2v[0], sav[0]);
  rule_eval(dp4.y, dp4.z, tk4.y, true, g1v[1], g2v[1], sav[1]);
  rule_eval(dp4.z, dp4.w, tk4.z, true, g1v[2], g2v[2], sav[2]);
  float gg0 = g1v[0] + g2v[0];
  float dpn3 = __shfl_down(dp4.x, 1, 64);
  float ggn  = __shfl_down(gg0,  1, 64);

  // ---- LDS metadata writes ----
  if (lane == 0) { hk[wid] = k0; ndp0[wid] = dp4.x; ndp1[wid] = dp4.y; ntk[wid] = tk4.x; }
  if (is63) {
    twk[wid] = k3;
    twp[wid] = uni ? (Cp + Sp) : t3p;
    twg[wid] = uni ? (Cg + Sg) : t3g;
    wu_[wid] = (uni && open) ? 1 : 0;
  }
  if (tid == 0) { smeta[0] = k0; bnd[0] = 0.f; bnd[1] = 0.f; bnd[2] = 0.f; bnd[3] = 0.f; }
  if (tid == TPB - 1) smeta[1] = k3;
  __syncthreads();

  // cross-wave carry (wave-uniform walk, <=3 steps)
  {
    const int myh = hk[wid];
    float Wp = 0.f, Wg = 0.f;
    for (int u = wid - 1; u >= 0; --u) {
      if (twk[u] != myh) break;
      Wp += twp[u]; Wg += twg[u];
      if (!wu_[u]) break;
    }
    if (open) { Cp += Wp; Cg += Wg; }
  }

  // lane-63 rule neighbor: LDS handoff from next wave (or own global loads at block end)
  if (is63) {
    float a0, a1; int t0;
    if (tid == TPB - 1) { a0 = nb_dp; a1 = nb_dp1; t0 = nb_tk; }
    else                { a0 = ndp0[wid + 1]; a1 = ndp1[wid + 1]; t0 = ntk[wid + 1]; }
    float ng1, ng2, ns_;
    rule_eval(a0, a1, t0, base + 4 < Tn - 1, ng1, ng2, ns_);
    dpn3 = a0; ggn = ng1 + ng2;
  }
  rule_eval(dp4.w, dpn3, tk4.w, base + 3 < Tn - 1, g1v[3], g2v[3], sav[3]);

  // pdur + rules losses
  float dpx[4] = {dp4.x, dp4.y, dp4.z, dp4.w};
  float dgl[4] = {g0, g1_, g2_, g3_};
  float addv[4] = {g1v[1] + g2v[1], g1v[2] + g2v[2], g1v[3] + g2v[3],
                   (base + 3 < Tn - 1) ? ggn : 0.f};
  float pdur_s = 0.f, rules_s = 0.f;
  #pragma unroll
  for (int j = 0; j < 4; ++j) {
    float dp = dpx[j];
    float dr = dp - sav[j] + addv[j];
    float lp = __logf(dp + 1.f);
    float dlr = lp - __logf(dr + 1.f);
    rules_s += dlr * dlr;
    float dlg = lp - __logf(dgl[j] + 1.f);
    pdur_s += dlg * dlg;
  }

  // run-compress with carry; owner thread finalizes each completed word
  const int wf = smeta[0], wl = smeta[1];
  const int nk_true = is63 ? ((tid == TPB - 1) ? -1 : hk[wid + 1]) : nk0;
  float wd_s = 0.f;
  {
    const int   kk[4] = {k0, k1, k2, k3};
    const float pp[4] = {p0, p1, p2, p3};
    const float gg[4] = {g0, g1_, g2_, g3_};
    int cur = k0; float ap = Cp, ag = Cg;
    #pragma unroll
    for (int j = 0; j < 4; ++j) {
      if (kk[j] != cur) {
        if (cur == wl)      { bnd[2] = ap; bnd[3] = ag; }   // unique writer (proven)
        else if (cur == wf) { bnd[0] = ap; bnd[1] = ag; }   // unique writer (proven)
        else { float d = __logf(ap + 1.f) - __logf(ag + 1.f); wd_s += d * d; }
        cur = kk[j]; ap = 0.f; ag = 0.f;
      }
      ap += pp[j]; ag += gg[j];
    }
    if (nk_true != cur) {            // run ends at my last element -> I own it
      if (cur == wl)      { bnd[2] = ap; bnd[3] = ag; }
      else if (cur == wf) { bnd[0] = ap; bnd[1] = ag; }
      else { float d = __logf(ap + 1.f) - __logf(ag + 1.f); wd_s += d * d; }
    }
    // else: run continues; downstream owner's carry already covers my part
  }

  // single weighted reduction (sp/sg are free: lane-63 prefix values)
  float x = 0.6f * pdur_s + 0.3f * rules_s + WDC * wd_s;
  x = wave_reduce(x);
  if (lane == 0) red[wid][0] = x;
  if (is63) { red[wid][1] = Pp; red[wid][2] = Pg; }
  __syncthreads();

  if (tid == 0) {
    float xs = 0.f, sp = 0.f, sg = 0.f;
    #pragma unroll
    for (int w = 0; w < NW; ++w) { xs += red[w][0]; sp += red[w][1]; sg += red[w][2]; }
    float4 a, b, c;
    a.x = xs; a.y = sp; a.z = sg; a.w = 0.f;
    const bool single = (wf == wl);
    b.x = bnd[0]; b.y = bnd[1]; b.z = __int_as_float(single ? -1 : wf); b.w = 0.f;
    c.x = bnd[2]; c.y = bnd[3]; c.z = __int_as_float(wl); c.w = 0.f;
    const size_t idx = (size_t)blockIdx.x * 3;
    partials[idx]     = a;
    partials[idx + 1] = b;
    partials[idx + 2] = c;
  }
}

// One block: thread r folds row r's BPR partials; boundary words arrive in
// non-decreasing id order, each spanning <=2 blocks -> ordered run-merge.
__global__ __launch_bounds__(1024) void finalize_kernel(
    const float4* __restrict__ partials, float* __restrict__ out)
{
  __shared__ double wsum[16];
  const int r = threadIdx.x;            // one row per thread
  double xs = 0.0, wdb = 0.0;
  float sp = 0.f, sg = 0.f;
  int curid = -1; float cp = 0.f, cg = 0.f;

  #pragma unroll
  for (int j = 0; j < BPR; ++j) {
    const size_t idx = ((size_t)r * BPR + j) * 3;
    float4 a = partials[idx];
    float4 b = partials[idx + 1];
    float4 c = partials[idx + 2];
    xs += (double)a.x; sp += a.y; sg += a.z;
    const int wfi = __float_as_int(b.z);
    const int wla = __float_as_int(c.z);
    if (wfi >= 0) {
      if (wfi != curid) {
        if (curid > 0) { float d = __logf(cp + 1.f) - __logf(cg + 1.f); wdb += (double)(d * d); }
        curid = wfi; cp = 0.f; cg = 0.f;
      }
      cp += b.x; cg += b.y;
    }
    if (wla >= 0) {
      if (wla != curid) {
        if (curid > 0) { float d = __logf(cp + 1.f) - __logf(cg + 1.f); wdb += (double)(d * d); }
        curid = wla; cp = 0.f; cg = 0.f;
      }
      cp += c.x; cg += c.y;
    }
  }
  if (curid > 0) { float d = __logf(cp + 1.f) - __logf(cg + 1.f); wdb += (double)(d * d); }

  float ds = __logf(sp + 1.f) - __logf(sg + 1.f);
  double contrib = xs / ((double)Bn * (double)Tn)
                 + 0.3 * wdb / ((double)Bn * (double)(Wn - 1))
                 + 0.1 * (double)(ds * ds) / (double)Bn;

  #pragma unroll
  for (int o = 32; o > 0; o >>= 1) contrib += __shfl_down(contrib, o, 64);
  if ((threadIdx.x & 63) == 0) wsum[threadIdx.x >> 6] = contrib;
  __syncthreads();
  if (threadIdx.x == 0) {
    double t = 0.0;
    #pragma unroll
    for (int i = 0; i < 16; ++i) t += wsum[i];
    out[0] = (float)t;
  }
}

extern "C" void kernel_launch(void* const* d_in, const int* in_sizes, int n_in,
                              void* d_out, int out_size, void* d_ws, size_t ws_size,
                              hipStream_t stream) {
  const float* dur_pred = (const float*)d_in[0];
  const float* dur_gt   = (const float*)d_in[1];
  const int*   ph2word  = (const int*)d_in[2];
  const int*   txt      = (const int*)d_in[3];

  // workspace: 8192 blocks x 48 B = 384 KB, fully overwritten (no memset)
  float4* partials = (float4*)d_ws;

  loss_kernel<<<Bn * BPR, TPB, 0, stream>>>(dur_pred, dur_gt, ph2word, txt, partials);
  finalize_kernel<<<1, 1024, 0, stream>>>(partials, (float*)d_out);
}

// Round 9
// 159.850 us; speedup vs baseline: 3.0008x; 1.0490x over previous
//
#include <hip/hip_runtime.h>

constexpr int Bn  = 1024;
constexpr int Tn  = 8192;
constexpr int Wn  = 2048;   // NUM_WORDS
constexpr int TPB = 256;
constexpr int NW  = TPB / 64;         // 4 waves per block
constexpr int EPT = 8;                // elements per thread (2 x float4)
constexpr int SEG = TPB * EPT;        // 2048 elements per block
constexpr int BPR = Tn / SEG;         // 4 blocks per row
static_assert(BPR == 4, "blockIdx decode uses >>2 / &3");
// fold wd into the per-block weighted scalar: 0.3*wd/(Bn*(Wn-1)) == WDC*wd/(Bn*Tn)
constexpr float WDC = 0.3f * (float)Tn / (float)(Wn - 1);

// Per-position rule evaluation (matches the vectorized reference exactly)
__device__ __forceinline__ void rule_eval(float dp, float dpn, int tok, bool valid_next,
                                          float& g1, float& g2, float& sa) {
  float expected;
  bool in_init = true;
  switch (tok) {
    case 94:  expected = 2.f; break;
    case 122: expected = 3.f; break;
    case 100: expected = 2.f; break;
    case 92:  expected = 2.f; break;
    case 43:  expected = 5.f; break;
    case 27:  expected = 5.f; break;
    default:  expected = 0.f; in_init = false; break;
  }
  float t1 = dp - expected;
  bool fire1 = in_init && (t1 > 0.f);
  g1 = fire1 ? t1 : 0.f;
  bool in_ratio = (tok == 44) | (tok == 28) | (tok == 29) |
                  (tok == 27) | (tok == 121) | (tok == 43);
  bool fire2 = in_ratio && valid_next && (3.f * dp > dpn);
  g2 = fire2 ? (dp - dpn * (1.f / 3.f)) : 0.f;
  sa = fire2 ? g2 : (fire1 ? g1 : 0.f);
}

__device__ __forceinline__ float wave_reduce(float v) {
  #pragma unroll
  for (int o = 32; o > 0; o >>= 1) v += __shfl_down(v, o, 64);
  return v;
}

// In-register segmented reduction over sorted keys, 8 elems/thread: the wave
// scan/carry machinery amortizes over 2x the elements vs the 4-elem version.
__global__ __launch_bounds__(TPB, 6) void loss_kernel(
    const float* __restrict__ dur_pred, const float* __restrict__ dur_gt,
    const int* __restrict__ ph2word, const int* __restrict__ txt,
    float4* __restrict__ partials)
{
  __shared__ int   hk[NW];                 // head key (kw[0] of lane 0) per wave
  __shared__ float ndp0[NW], ndp1[NW];     // lane0's dp[0]/dp[1] (rule handoff)
  __shared__ int   ntk[NW];                // lane0's tk[0]
  __shared__ int   twk[NW];                // wave tail-run key
  __shared__ float twp[NW], twg[NW];       // wave tail-run in-wave sums
  __shared__ int   wu_[NW];                // wave is entirely one open run
  __shared__ float bnd[4];                 // {wf_p, wf_g, wl_p, wl_g}
  __shared__ int   smeta[2];               // {wf, wl}
  __shared__ float red[NW][3];             // {x, sp_wave, sg_wave}

  const int row = blockIdx.x >> 2;
  const int sub = blockIdx.x & 3;
  const int s = sub * SEG;
  const size_t roff = (size_t)row * Tn;
  const float* __restrict__ dpr = dur_pred + roff;
  const float* __restrict__ dgr = dur_gt + roff;
  const int*   __restrict__ pwr = ph2word + roff;
  const int*   __restrict__ tkr = txt + roff;

  const int tid  = threadIdx.x;
  const int lane = tid & 63;
  const int wid  = tid >> 6;
  const bool is63 = (lane == 63);
  const int base = s + tid * EPT;

  // ---- load phase: 8 x 16B vector loads, all issued up front ----
  const float4 dpA = *reinterpret_cast<const float4*>(dpr + base);
  const float4 dpB = *reinterpret_cast<const float4*>(dpr + base + 4);
  const float4 dgA = *reinterpret_cast<const float4*>(dgr + base);
  const float4 dgB = *reinterpret_cast<const float4*>(dgr + base + 4);
  const int4   pwA = *reinterpret_cast<const int4*>(pwr + base);
  const int4   pwB = *reinterpret_cast<const int4*>(pwr + base + 4);
  const int4   tkA = *reinterpret_cast<const int4*>(tkr + base);
  const int4   tkB = *reinterpret_cast<const int4*>(tkr + base + 4);

  // block-last thread: rule-neighbor from the next block's region
  float nb_dp = 0.f, nb_dp1 = 0.f; int nb_tk = -1;
  if (tid == TPB - 1) {
    const int p = base + EPT;
    if (p < Tn) { nb_dp = dpr[p]; nb_dp1 = dpr[p + 1]; nb_tk = tkr[p]; }
  }

  const float dp[8] = {dpA.x,dpA.y,dpA.z,dpA.w,dpB.x,dpB.y,dpB.z,dpB.w};
  const float dg[8] = {dgA.x,dgA.y,dgA.z,dgA.w,dgB.x,dgB.y,dgB.z,dgB.w};
  const int   kw[8] = {pwA.x,pwA.y,pwA.z,pwA.w,pwB.x,pwB.y,pwB.z,pwB.w};
  const int   tk[8] = {tkA.x,tkA.y,tkA.z,tkA.w,tkB.x,tkB.y,tkB.z,tkB.w};

  float pm[8];
  #pragma unroll
  for (int j = 0; j < 8; ++j) pm[j] = fmaxf(dp[j], 0.f);

  float Sp = 0.f, Sg = 0.f;
  #pragma unroll
  for (int j = 0; j < 8; ++j) { Sp += pm[j]; Sg += dg[j]; }

  // trailing-run sums within this thread (elements with key == kw[7]); sorted
  // keys make the chain prefix-closed
  float t3p = pm[7], t3g = dg[7];
  if (kw[6]==kw[7]) { t3p+=pm[6]; t3g+=dg[6];
  if (kw[5]==kw[7]) { t3p+=pm[5]; t3g+=dg[5];
  if (kw[4]==kw[7]) { t3p+=pm[4]; t3g+=dg[4];
  if (kw[3]==kw[7]) { t3p+=pm[3]; t3g+=dg[3];
  if (kw[2]==kw[7]) { t3p+=pm[2]; t3g+=dg[2];
  if (kw[1]==kw[7]) { t3p+=pm[1]; t3g+=dg[1];
  if (kw[0]==kw[7]) { t3p+=pm[0]; t3g+=dg[0]; }}}}}}}

  // inclusive prefix scans of full-thread sums (lane63 -> wave sp/sg for free)
  float Pp = Sp, Pg = Sg;
  #pragma unroll
  for (int o = 1; o < 64; o <<= 1) {
    float tp = __shfl_up(Pp, o, 64);
    float tg = __shfl_up(Pg, o, 64);
    if (lane >= o) { Pp += tp; Pg += tg; }
  }

  // carry-in for the run containing my element 0 (identical proof to the
  // 4-elem version; sortedness makes uniform == kw[0]==kw[7])
  const int nk0 = __shfl_down(kw[0], 1, 64);     // lanes 0..62 valid
  const bool uni = (kw[0] == kw[7]);
  const bool cn  = uni && (kw[7] == nk0);        // continues into next lane
  const unsigned long long cmask = __ballot(cn);
  const unsigned long long below = (1ull << lane) - 1ull;
  const unsigned long long y = (~cmask) & below;
  const int L = y ? (64 - __clzll(y)) : 0;       // first lane of my carry range
  const int Lm1 = (L > 0) ? (L - 1) : 0;
  const float Ppm1 = __shfl_up(Pp, 1, 64);
  const float Pgm1 = __shfl_up(Pg, 1, 64);
  const float PpL = __shfl(Pp, Lm1, 64);
  const float PgL = __shfl(Pg, Lm1, 64);
  const int   k7L = __shfl(kw[7], Lm1, 64);
  const float tpL = __shfl(t3p, Lm1, 64);
  const float tgL = __shfl(t3g, Lm1, 64);
  float Cp = 0.f, Cg = 0.f;
  if (L < lane) {                                 // full uniform threads [L, lane-1]
    Cp = Ppm1 - (L > 0 ? PpL : 0.f);
    Cg = Pgm1 - (L > 0 ? PgL : 0.f);
  }
  if (L > 0 && k7L == kw[0]) { Cp += tpL; Cg += tgL; }  // partial tail of L-1
  const bool open = (y == 0);

  // first rule eval + neighbor shuffles (next thread's elem0 data)
  float g1v0, g2v0, sa0;
  rule_eval(dp[0], dp[1], tk[0], true, g1v0, g2v0, sa0);
  const float gg0 = g1v0 + g2v0;
  float dpn7 = __shfl_down(dp[0], 1, 64);
  float ggn  = __shfl_down(gg0,  1, 64);

  // ---- LDS metadata ----
  if (lane == 0) { hk[wid]=kw[0]; ndp0[wid]=dp[0]; ndp1[wid]=dp[1]; ntk[wid]=tk[0]; }
  if (is63) {
    twk[wid] = kw[7];
    twp[wid] = uni ? (Cp + Sp) : t3p;
    twg[wid] = uni ? (Cg + Sg) : t3g;
    wu_[wid] = (uni && open) ? 1 : 0;
  }
  if (tid == 0) { smeta[0]=kw[0]; bnd[0]=0.f; bnd[1]=0.f; bnd[2]=0.f; bnd[3]=0.f; }
  if (tid == TPB - 1) smeta[1] = kw[7];
  __syncthreads();

  // cross-wave carry (wave-uniform walk, <=3 steps)
  {
    const int myh = hk[wid];
    float Wp = 0.f, Wg = 0.f;
    for (int u = wid - 1; u >= 0; --u) {
      if (twk[u] != myh) break;
      Wp += twp[u]; Wg += twg[u];
      if (!wu_[u]) break;
    }
    if (open) { Cp += Wp; Cg += Wg; }
  }

  // lane-63 rule neighbor: LDS handoff from next wave (block-last: own loads)
  if (is63) {
    float a0, a1; int t0;
    if (tid == TPB - 1) { a0 = nb_dp; a1 = nb_dp1; t0 = nb_tk; }
    else                { a0 = ndp0[wid + 1]; a1 = ndp1[wid + 1]; t0 = ntk[wid + 1]; }
    float ng1, ng2, ns_;
    rule_eval(a0, a1, t0, base + EPT < Tn - 1, ng1, ng2, ns_);
    dpn7 = a0; ggn = ng1 + ng2;
  }

  // pdur + rules losses: rolling 2-state rule chain (no sa[8]/gg[8] arrays)
  float pdur_s = 0.f, rules_s = 0.f;
  float sa_prev = sa0;
  #pragma unroll
  for (int j = 1; j < 8; ++j) {
    float g1n, g2n, san;
    const float dpn = (j < 7) ? dp[j + 1] : dpn7;
    const bool vn = (j < 7) ? true : (base + 7 < Tn - 1);
    rule_eval(dp[j], dpn, tk[j], vn, g1n, g2n, san);
    // finish element j-1 (its add = gg[j]; j-1 <= 6 always has a next position)
    const float d0 = dp[j - 1];
    const float dr = d0 - sa_prev + (g1n + g2n);
    const float lp = __logf(d0 + 1.f);
    const float dlr = lp - __logf(dr + 1.f);
    rules_s += dlr * dlr;
    const float dlg = lp - __logf(dg[j - 1] + 1.f);
    pdur_s += dlg * dlg;
    sa_prev = san;
  }
  {
    const float add7 = (base + 7 < Tn - 1) ? ggn : 0.f;
    const float d0 = dp[7];
    const float dr = d0 - sa_prev + add7;
    const float lp = __logf(d0 + 1.f);
    const float dlr = lp - __logf(dr + 1.f);
    rules_s += dlr * dlr;
    const float dlg = lp - __logf(dg[7] + 1.f);
    pdur_s += dlg * dlg;
  }

  // run-compress with carry; owner thread finalizes each completed word
  const int wf = smeta[0], wl = smeta[1];
  const int nk_true = is63 ? ((tid == TPB - 1) ? -1 : hk[wid + 1]) : nk0;
  float wd_s = 0.f;
  {
    int cur = kw[0]; float ap = Cp, ag = Cg;
    #pragma unroll
    for (int j = 0; j < 8; ++j) {
      if (kw[j] != cur) {
        if (cur == wl)      { bnd[2] = ap; bnd[3] = ag; }   // unique writer
        else if (cur == wf) { bnd[0] = ap; bnd[1] = ag; }   // unique writer
        else { const float d = __logf(ap + 1.f) - __logf(ag + 1.f); wd_s += d * d; }
        cur = kw[j]; ap = 0.f; ag = 0.f;
      }
      ap += pm[j]; ag += dg[j];
    }
    if (nk_true != cur) {            // run ends at my last element -> I own it
      if (cur == wl)      { bnd[2] = ap; bnd[3] = ag; }
      else if (cur == wf) { bnd[0] = ap; bnd[1] = ag; }
      else { const float d = __logf(ap + 1.f) - __logf(ag + 1.f); wd_s += d * d; }
    }
  }

  // single weighted reduction (sp/sg free: lane-63 inclusive prefix values)
  float x = 0.6f * pdur_s + 0.3f * rules_s + WDC * wd_s;
  x = wave_reduce(x);
  if (lane == 0) red[wid][0] = x;
  if (is63) { red[wid][1] = Pp; red[wid][2] = Pg; }
  __syncthreads();

  if (tid == 0) {
    float xs = 0.f, sp = 0.f, sg = 0.f;
    #pragma unroll
    for (int w = 0; w < NW; ++w) { xs += red[w][0]; sp += red[w][1]; sg += red[w][2]; }
    float4 a, b, c;
    a.x = xs; a.y = sp; a.z = sg; a.w = 0.f;
    const bool single = (wf == wl);
    b.x = bnd[0]; b.y = bnd[1]; b.z = __int_as_float(single ? -1 : wf); b.w = 0.f;
    c.x = bnd[2]; c.y = bnd[3]; c.z = __int_as_float(wl); c.w = 0.f;
    const size_t idx = (size_t)blockIdx.x * 3;
    partials[idx]     = a;
    partials[idx + 1] = b;
    partials[idx + 2] = c;
  }
}

// One block: thread r folds row r's BPR partials; boundary words arrive in
// non-decreasing id order, each spanning <=2 blocks -> ordered run-merge.
__global__ __launch_bounds__(1024) void finalize_kernel(
    const float4* __restrict__ partials, float* __restrict__ out)
{
  __shared__ double wsum[16];
  const int r = threadIdx.x;            // one row per thread
  double xs = 0.0, wdb = 0.0;
  float sp = 0.f, sg = 0.f;
  int curid = -1; float cp = 0.f, cg = 0.f;

  #pragma unroll
  for (int j = 0; j < BPR; ++j) {
    const size_t idx = ((size_t)r * BPR + j) * 3;
    float4 a = partials[idx];
    float4 b = partials[idx + 1];
    float4 c = partials[idx + 2];
    xs += (double)a.x; sp += a.y; sg += a.z;
    const int wfi = __float_as_int(b.z);
    const int wla = __float_as_int(c.z);
    if (wfi >= 0) {
      if (wfi != curid) {
        if (curid > 0) { float d = __logf(cp + 1.f) - __logf(cg + 1.f); wdb += (double)(d * d); }
        curid = wfi; cp = 0.f; cg = 0.f;
      }
      cp += b.x; cg += b.y;
    }
    if (wla >= 0) {
      if (wla != curid) {
        if (curid > 0) { float d = __logf(cp + 1.f) - __logf(cg + 1.f); wdb += (double)(d * d); }
        curid = wla; cp = 0.f; cg = 0.f;
      }
      cp += c.x; cg += c.y;
    }
  }
  if (curid > 0) { float d = __logf(cp + 1.f) - __logf(cg + 1.f); wdb += (double)(d * d); }

  float ds = __logf(sp + 1.f) - __logf(sg + 1.f);
  double contrib = xs / ((double)Bn * (double)Tn)
                 + 0.3 * wdb / ((double)Bn * (double)(Wn - 1))
                 + 0.1 * (double)(ds * ds) / (double)Bn;

  #pragma unroll
  for (int o = 32; o > 0; o >>= 1) contrib += __shfl_down(contrib, o, 64);
  if ((threadIdx.x & 63) == 0) wsum[threadIdx.x >> 6] = contrib;
  __syncthreads();
  if (threadIdx.x == 0) {
    double t = 0.0;
    #pragma unroll
    for (int i = 0; i < 16; ++i) t += wsum[i];
    out[0] = (float)t;
  }
}

extern "C" void kernel_launch(void* const* d_in, const int* in_sizes, int n_in,
                              void* d_out, int out_size, void* d_ws, size_t ws_size,
                              hipStream_t stream) {
  const float* dur_pred = (const float*)d_in[0];
  const float* dur_gt   = (const float*)d_in[1];
  const int*   ph2word  = (const int*)d_in[2];
  const int*   txt      = (const int*)d_in[3];

  // workspace: 4096 blocks x 48 B = 192 KB, fully overwritten (no memset)
  float4* partials = (float4*)d_ws;

  loss_kernel<<<Bn * BPR, TPB, 0, stream>>>(dur_pred, dur_gt, ph2word, txt, partials);
  finalize_kernel<<<1, 1024, 0, stream>>>(partials, (float*)d_out);
}

// Round 10
// 158.767 us; speedup vs baseline: 3.0213x; 1.0068x over previous
//
#include <hip/hip_runtime.h>

constexpr int Bn  = 1024;
constexpr int Tn  = 8192;
constexpr int Wn  = 2048;   // NUM_WORDS
constexpr int TPB = 512;
constexpr int NW  = TPB / 64;         // 8 waves per block
constexpr int EPT = 4;                // elements per thread (proven fastest, R8)
constexpr int SEG = TPB * EPT;        // 2048 elements per block
constexpr int BPR = Tn / SEG;         // 4 blocks per row
static_assert(BPR == 4, "blockIdx decode uses >>2 / &3");
// fold wd into the per-block weighted scalar: 0.3*wd/(Bn*(Wn-1)) == WDC*wd/(Bn*Tn)
constexpr float WDC = 0.3f * (float)Tn / (float)(Wn - 1);

// Per-position rule evaluation (matches the vectorized reference exactly)
__device__ __forceinline__ void rule_eval(float dp, float dpn, int tok, bool valid_next,
                                          float& g1, float& g2, float& sa) {
  float expected;
  bool in_init = true;
  switch (tok) {
    case 94:  expected = 2.f; break;
    case 122: expected = 3.f; break;
    case 100: expected = 2.f; break;
    case 92:  expected = 2.f; break;
    case 43:  expected = 5.f; break;
    case 27:  expected = 5.f; break;
    default:  expected = 0.f; in_init = false; break;
  }
  float t1 = dp - expected;
  bool fire1 = in_init && (t1 > 0.f);
  g1 = fire1 ? t1 : 0.f;
  bool in_ratio = (tok == 44) | (tok == 28) | (tok == 29) |
                  (tok == 27) | (tok == 121) | (tok == 43);
  bool fire2 = in_ratio && valid_next && (3.f * dp > dpn);
  g2 = fire2 ? (dp - dpn * (1.f / 3.f)) : 0.f;
  sa = fire2 ? g2 : (fire1 ? g1 : 0.f);
}

__device__ __forceinline__ float wave_reduce(float v) {
  #pragma unroll
  for (int o = 32; o > 0; o >>= 1) v += __shfl_down(v, o, 64);
  return v;
}

// R8's per-thread structure (EPT=4, in-register segmented reduction over sorted
// keys) at TPB=512 -> BPR=4: halves block count and halves finalize work.
__global__ __launch_bounds__(TPB, 4) void loss_kernel(
    const float* __restrict__ dur_pred, const float* __restrict__ dur_gt,
    const int* __restrict__ ph2word, const int* __restrict__ txt,
    float4* __restrict__ partials)
{
  __shared__ int   hk[NW];                 // head key (k0 of lane 0) per wave
  __shared__ float ndp0[NW], ndp1[NW];     // lane0's dp4.x/.y  (rule neighbor handoff)
  __shared__ int   ntk[NW];                // lane0's tk4.x
  __shared__ int   twk[NW];                // wave tail-run key
  __shared__ float twp[NW], twg[NW];       // wave tail-run in-wave sums
  __shared__ int   wu_[NW];                // wave is entirely one open run
  __shared__ float bnd[4];                 // {wf_p, wf_g, wl_p, wl_g}
  __shared__ int   smeta[2];               // {wf, wl}
  __shared__ float red[NW][3];             // {x, sp_wave, sg_wave}

  const int row = blockIdx.x >> 2;
  const int sub = blockIdx.x & 3;
  const int s = sub * SEG;
  const size_t roff = (size_t)row * Tn;
  const float* __restrict__ dpr = dur_pred + roff;
  const float* __restrict__ dgr = dur_gt + roff;
  const int*   __restrict__ pwr = ph2word + roff;
  const int*   __restrict__ tkr = txt + roff;

  const int tid  = threadIdx.x;
  const int lane = tid & 63;
  const int wid  = tid >> 6;
  const bool is63 = (lane == 63);
  const int base = s + tid * EPT;

  // ---- load phase ----
  float4 dp4 = *reinterpret_cast<const float4*>(dpr + base);
  float4 dg4 = *reinterpret_cast<const float4*>(dgr + base);
  int4   pw4 = *reinterpret_cast<const int4*>(pwr + base);
  int4   tk4 = *reinterpret_cast<const int4*>(tkr + base);

  // block-last thread: rule-neighbor comes from the next block's region
  float nb_dp = 0.f, nb_dp1 = 0.f; int nb_tk = -1;
  if (tid == TPB - 1) {
    const int p = base + EPT;
    if (p < Tn) { nb_dp = dpr[p]; nb_dp1 = dpr[p + 1]; nb_tk = tkr[p]; }
  }

  const int k0 = pw4.x, k1 = pw4.y, k2 = pw4.z, k3 = pw4.w;
  const float p0 = fmaxf(dp4.x, 0.f), p1 = fmaxf(dp4.y, 0.f),
              p2 = fmaxf(dp4.z, 0.f), p3 = fmaxf(dp4.w, 0.f);
  const float g0 = dg4.x, g1_ = dg4.y, g2_ = dg4.z, g3_ = dg4.w;
  const float Sp = p0 + p1 + p2 + p3;
  const float Sg = g0 + g1_ + g2_ + g3_;

  // trailing-run partial sums within this thread (elements with key == k3)
  float t3p = p3, t3g = g3_;
  if (k2 == k3) { t3p += p2; t3g += g2_;
    if (k1 == k3) { t3p += p1; t3g += g1_;
      if (k0 == k3) { t3p += p0; t3g += g0; } } }

  // inclusive prefix scans of full-thread sums (lane63 -> wave sp/sg for free)
  float Pp = Sp, Pg = Sg;
  #pragma unroll
  for (int o = 1; o < 64; o <<= 1) {
    float tp = __shfl_up(Pp, o, 64);
    float tg = __shfl_up(Pg, o, 64);
    if (lane >= o) { Pp += tp; Pg += tg; }
  }

  // carry-in for the run containing my element 0
  const int nk0 = __shfl_down(k0, 1, 64);        // lanes 0..62 valid
  const bool uni = (k0 == k3);
  const bool cn  = uni && (k3 == nk0);           // continues into next lane
  const unsigned long long cmask = __ballot(cn);
  const unsigned long long below = (1ull << lane) - 1ull;
  const unsigned long long y = (~cmask) & below;
  const int L = y ? (64 - __clzll(y)) : 0;       // first lane of my carry range
  const int Lm1 = (L > 0) ? (L - 1) : 0;
  const float Ppm1 = __shfl_up(Pp, 1, 64);
  const float Pgm1 = __shfl_up(Pg, 1, 64);
  const float PpL = __shfl(Pp, Lm1, 64);
  const float PgL = __shfl(Pg, Lm1, 64);
  const int   k3L = __shfl(k3, Lm1, 64);
  const float tpL = __shfl(t3p, Lm1, 64);
  const float tgL = __shfl(t3g, Lm1, 64);
  float Cp = 0.f, Cg = 0.f;
  if (L < lane) {                                 // full uniform threads [L, lane-1]
    Cp = Ppm1 - (L > 0 ? PpL : 0.f);
    Cg = Pgm1 - (L > 0 ? PgL : 0.f);
  }
  if (L > 0 && k3L == k0) {                       // partial tail of thread L-1
    Cp += tpL; Cg += tgL;
  }
  const bool open = (y == 0);                     // run chains to wave start

  // rules j=0..2 (in-register neighbors)
  float g1v[4], g2v[4], sav[4];
  rule_eval(dp4.x, dp4.y, tk4.x, true, g1v[0], g2v[0], sav[0]);
  rule_eval(dp4.y, dp4.z, tk4.y, true, g1v[1], g2v[1], sav[1]);
  rule_eval(dp4.z, dp4.w, tk4.z, true, g1v[2], g2v[2], sav[2]);
  float gg0 = g1v[0] + g2v[0];
  float dpn3 = __shfl_down(dp4.x, 1, 64);
  float ggn  = __shfl_down(gg0,  1, 64);

  // ---- LDS metadata ----
  if (lane == 0) { hk[wid] = k0; ndp0[wid] = dp4.x; ndp1[wid] = dp4.y; ntk[wid] = tk4.x; }
  if (is63) {
    twk[wid] = k3;
    twp[wid] = uni ? (Cp + Sp) : t3p;
    twg[wid] = uni ? (Cg + Sg) : t3g;
    wu_[wid] = (uni && open) ? 1 : 0;
  }
  if (tid == 0) { smeta[0] = k0; bnd[0] = 0.f; bnd[1] = 0.f; bnd[2] = 0.f; bnd[3] = 0.f; }
  if (tid == TPB - 1) smeta[1] = k3;
  __syncthreads();

  // cross-wave carry (wave-uniform walk, <=NW-1 steps)
  {
    const int myh = hk[wid];
    float Wp = 0.f, Wg = 0.f;
    for (int u = wid - 1; u >= 0; --u) {
      if (twk[u] != myh) break;
      Wp += twp[u]; Wg += twg[u];
      if (!wu_[u]) break;
    }
    if (open) { Cp += Wp; Cg += Wg; }
  }

  // lane-63 rule neighbor: LDS handoff from next wave (block-last: own loads)
  if (is63) {
    float a0, a1; int t0;
    if (tid == TPB - 1) { a0 = nb_dp; a1 = nb_dp1; t0 = nb_tk; }
    else                { a0 = ndp0[wid + 1]; a1 = ndp1[wid + 1]; t0 = ntk[wid + 1]; }
    float ng1, ng2, ns_;
    rule_eval(a0, a1, t0, base + EPT < Tn - 1, ng1, ng2, ns_);
    dpn3 = a0; ggn = ng1 + ng2;
  }
  rule_eval(dp4.w, dpn3, tk4.w, base + 3 < Tn - 1, g1v[3], g2v[3], sav[3]);

  // pdur + rules losses
  float dpx[4] = {dp4.x, dp4.y, dp4.z, dp4.w};
  float dgl[4] = {g0, g1_, g2_, g3_};
  float addv[4] = {g1v[1] + g2v[1], g1v[2] + g2v[2], g1v[3] + g2v[3],
                   (base + 3 < Tn - 1) ? ggn : 0.f};
  float pdur_s = 0.f, rules_s = 0.f;
  #pragma unroll
  for (int j = 0; j < 4; ++j) {
    float dp = dpx[j];
    float dr = dp - sav[j] + addv[j];
    float lp = __logf(dp + 1.f);
    float dlr = lp - __logf(dr + 1.f);
    rules_s += dlr * dlr;
    float dlg = lp - __logf(dgl[j] + 1.f);
    pdur_s += dlg * dlg;
  }

  // run-compress with carry; owner thread finalizes each completed word
  const int wf = smeta[0], wl = smeta[1];
  const int nk_true = is63 ? ((tid == TPB - 1) ? -1 : hk[wid + 1]) : nk0;
  float wd_s = 0.f;
  {
    const int   kk[4] = {k0, k1, k2, k3};
    const float pp[4] = {p0, p1, p2, p3};
    const float gg[4] = {g0, g1_, g2_, g3_};
    int cur = k0; float ap = Cp, ag = Cg;
    #pragma unroll
    for (int j = 0; j < 4; ++j) {
      if (kk[j] != cur) {
        if (cur == wl)      { bnd[2] = ap; bnd[3] = ag; }   // unique writer
        else if (cur == wf) { bnd[0] = ap; bnd[1] = ag; }   // unique writer
        else { float d = __logf(ap + 1.f) - __logf(ag + 1.f); wd_s += d * d; }
        cur = kk[j]; ap = 0.f; ag = 0.f;
      }
      ap += pp[j]; ag += gg[j];
    }
    if (nk_true != cur) {            // run ends at my last element -> I own it
      if (cur == wl)      { bnd[2] = ap; bnd[3] = ag; }
      else if (cur == wf) { bnd[0] = ap; bnd[1] = ag; }
      else { float d = __logf(ap + 1.f) - __logf(ag + 1.f); wd_s += d * d; }
    }
  }

  // single weighted reduction (sp/sg free: lane-63 inclusive prefix values)
  float x = 0.6f * pdur_s + 0.3f * rules_s + WDC * wd_s;
  x = wave_reduce(x);
  if (lane == 0) red[wid][0] = x;
  if (is63) { red[wid][1] = Pp; red[wid][2] = Pg; }
  __syncthreads();

  if (tid == 0) {
    float xs = 0.f, sp = 0.f, sg = 0.f;
    #pragma unroll
    for (int w = 0; w < NW; ++w) { xs += red[w][0]; sp += red[w][1]; sg += red[w][2]; }
    float4 a, b, c;
    a.x = xs; a.y = sp; a.z = sg; a.w = 0.f;
    const bool single = (wf == wl);
    b.x = bnd[0]; b.y = bnd[1]; b.z = __int_as_float(single ? -1 : wf); b.w = 0.f;
    c.x = bnd[2]; c.y = bnd[3]; c.z = __int_as_float(wl); c.w = 0.f;
    const size_t idx = (size_t)blockIdx.x * 3;
    partials[idx]     = a;
    partials[idx + 1] = b;
    partials[idx + 2] = c;
  }
}

// One block: thread r folds row r's BPR partials; boundary words arrive in
// non-decreasing id order, each spanning <=2 blocks -> ordered run-merge.
__global__ __launch_bounds__(1024) void finalize_kernel(
    const float4* __restrict__ partials, float* __restrict__ out)
{
  __shared__ double wsum[16];
  const int r = threadIdx.x;            // one row per thread
  double xs = 0.0, wdb = 0.0;
  float sp = 0.f, sg = 0.f;
  int curid = -1; float cp = 0.f, cg = 0.f;

  #pragma unroll
  for (int j = 0; j < BPR; ++j) {
    const size_t idx = ((size_t)r * BPR + j) * 3;
    float4 a = partials[idx];
    float4 b = partials[idx + 1];
    float4 c = partials[idx + 2];
    xs += (double)a.x; sp += a.y; sg += a.z;
    const int wfi = __float_as_int(b.z);
    const int wla = __float_as_int(c.z);
    if (wfi >= 0) {
      if (wfi != curid) {
        if (curid > 0) { float d = __logf(cp + 1.f) - __logf(cg + 1.f); wdb += (double)(d * d); }
        curid = wfi; cp = 0.f; cg = 0.f;
      }
      cp += b.x; cg += b.y;
    }
    if (wla >= 0) {
      if (wla != curid) {
        if (curid > 0) { float d = __logf(cp + 1.f) - __logf(cg + 1.f); wdb += (double)(d * d); }
        curid = wla; cp = 0.f; cg = 0.f;
      }
      cp += c.x; cg += c.y;
    }
  }
  if (curid > 0) { float d = __logf(cp + 1.f) - __logf(cg + 1.f); wdb += (double)(d * d); }

  float ds = __logf(sp + 1.f) - __logf(sg + 1.f);
  double contrib = xs / ((double)Bn * (double)Tn)
                 + 0.3 * wdb / ((double)Bn * (double)(Wn - 1))
                 + 0.1 * (double)(ds * ds) / (double)Bn;

  #pragma unroll
  for (int o = 32; o > 0; o >>= 1) contrib += __shfl_down(contrib, o, 64);
  if ((threadIdx.x & 63) == 0) wsum[threadIdx.x >> 6] = contrib;
  __syncthreads();
  if (threadIdx.x == 0) {
    double t = 0.0;
    #pragma unroll
    for (int i = 0; i < 16; ++i) t += wsum[i];
    out[0] = (float)t;
  }
}

extern "C" void kernel_launch(void* const* d_in, const int* in_sizes, int n_in,
                              void* d_out, int out_size, void* d_ws, size_t ws_size,
                              hipStream_t stream) {
  const float* dur_pred = (const float*)d_in[0];
  const float* dur_gt   = (const float*)d_in[1];
  const int*   ph2word  = (const int*)d_in[2];
  const int*   txt      = (const int*)d_in[3];

  // workspace: 4096 blocks x 48 B = 192 KB, fully overwritten (no memset)
  float4* partials = (float4*)d_ws;

  loss_kernel<<<Bn * BPR, TPB, 0, stream>>>(dur_pred, dur_gt, ph2word, txt, partials);
  finalize_kernel<<<1, 1024, 0, stream>>>(partials, (float*)d_out);
}

// Round 11
// 155.209 us; speedup vs baseline: 3.0905x; 1.0229x over previous
//
#include <hip/hip_runtime.h>

constexpr int Bn  = 1024;
constexpr int Tn  = 8192;
constexpr int Wn  = 2048;   // NUM_WORDS
constexpr int TPB = 512;
constexpr int NW  = TPB / 64;         // 8 waves per block
constexpr int EPT = 4;                // elements per thread
constexpr int SEG = TPB * EPT;        // 2048 elements per block
constexpr int BPR = Tn / SEG;         // 4 blocks per row
static_assert(BPR == 4, "blockIdx decode uses >>2 / &3");
// fold wd into the per-block weighted scalar: 0.3*wd/(Bn*(Wn-1)) == WDC*wd/(Bn*Tn)
constexpr float WDC = 0.3f * (float)Tn / (float)(Wn - 1);

// Lean rule evaluation. Algebraically identical to the reference:
//   g1 = (in_init && dp-expected>0) ? dp-expected : 0
//   g2 = (in_ratio && valid_next && 3dp>dpn) ? dp-dpn/3 : 0
//   gg = g1+g2 ;  sa = fire2 ? g2 : (fire1 ? g1 : 0) == fire2 ? g2 : g1
// (g1 is already 0 when !fire1, so the inner select collapses.)
__device__ __forceinline__ void rule_eval2(float dp, float dpn, int tok, bool valid_next,
                                           float& gg, float& sa) {
  const bool t27 = (tok == 27), t43 = (tok == 43);
  const bool in_init = (tok == 94) | (tok == 122) | (tok == 100) | (tok == 92) | t43 | t27;
  const float expected = (tok == 122) ? 3.f : ((t43 | t27) ? 5.f : 2.f);
  const float t1 = dp - expected;
  const bool fire1 = in_init && (t1 > 0.f);
  const float g1 = fire1 ? t1 : 0.f;
  const bool in_ratio = (tok == 44) | (tok == 28) | (tok == 29) | t27 | (tok == 121) | t43;
  const bool fire2 = in_ratio && valid_next && (3.f * dp > dpn);
  const float g2 = fire2 ? (dp - dpn * (1.f / 3.f)) : 0.f;
  gg = g1 + g2;
  sa = fire2 ? g2 : g1;
}

__device__ __forceinline__ float wave_reduce(float v) {
  #pragma unroll
  for (int o = 32; o > 0; o >>= 1) v += __shfl_down(v, o, 64);
  return v;
}

// R10 structure: EPT=4 in-register segmented reduction over sorted keys,
// TPB=512 -> BPR=4. Only change vs R10: rule_eval2 (lean compares/selects).
__global__ __launch_bounds__(TPB, 4) void loss_kernel(
    const float* __restrict__ dur_pred, const float* __restrict__ dur_gt,
    const int* __restrict__ ph2word, const int* __restrict__ txt,
    float4* __restrict__ partials)
{
  __shared__ int   hk[NW];                 // head key (k0 of lane 0) per wave
  __shared__ float ndp0[NW], ndp1[NW];     // lane0's dp4.x/.y  (rule neighbor handoff)
  __shared__ int   ntk[NW];                // lane0's tk4.x
  __shared__ int   twk[NW];                // wave tail-run key
  __shared__ float twp[NW], twg[NW];       // wave tail-run in-wave sums
  __shared__ int   wu_[NW];                // wave is entirely one open run
  __shared__ float bnd[4];                 // {wf_p, wf_g, wl_p, wl_g}
  __shared__ int   smeta[2];               // {wf, wl}
  __shared__ float red[NW][3];             // {x, sp_wave, sg_wave}

  const int row = blockIdx.x >> 2;
  const int sub = blockIdx.x & 3;
  const int s = sub * SEG;
  const size_t roff = (size_t)row * Tn;
  const float* __restrict__ dpr = dur_pred + roff;
  const float* __restrict__ dgr = dur_gt + roff;
  const int*   __restrict__ pwr = ph2word + roff;
  const int*   __restrict__ tkr = txt + roff;

  const int tid  = threadIdx.x;
  const int lane = tid & 63;
  const int wid  = tid >> 6;
  const bool is63 = (lane == 63);
  const int base = s + tid * EPT;

  // ---- load phase ----
  float4 dp4 = *reinterpret_cast<const float4*>(dpr + base);
  float4 dg4 = *reinterpret_cast<const float4*>(dgr + base);
  int4   pw4 = *reinterpret_cast<const int4*>(pwr + base);
  int4   tk4 = *reinterpret_cast<const int4*>(tkr + base);

  // block-last thread: rule-neighbor comes from the next block's region
  float nb_dp = 0.f, nb_dp1 = 0.f; int nb_tk = -1;
  if (tid == TPB - 1) {
    const int p = base + EPT;
    if (p < Tn) { nb_dp = dpr[p]; nb_dp1 = dpr[p + 1]; nb_tk = tkr[p]; }
  }

  const int k0 = pw4.x, k1 = pw4.y, k2 = pw4.z, k3 = pw4.w;
  const float p0 = fmaxf(dp4.x, 0.f), p1 = fmaxf(dp4.y, 0.f),
              p2 = fmaxf(dp4.z, 0.f), p3 = fmaxf(dp4.w, 0.f);
  const float g0 = dg4.x, g1_ = dg4.y, g2_ = dg4.z, g3_ = dg4.w;
  const float Sp = p0 + p1 + p2 + p3;
  const float Sg = g0 + g1_ + g2_ + g3_;

  // trailing-run partial sums within this thread (elements with key == k3)
  float t3p = p3, t3g = g3_;
  if (k2 == k3) { t3p += p2; t3g += g2_;
    if (k1 == k3) { t3p += p1; t3g += g1_;
      if (k0 == k3) { t3p += p0; t3g += g0; } } }

  // inclusive prefix scans of full-thread sums (lane63 -> wave sp/sg for free)
  float Pp = Sp, Pg = Sg;
  #pragma unroll
  for (int o = 1; o < 64; o <<= 1) {
    float tp = __shfl_up(Pp, o, 64);
    float tg = __shfl_up(Pg, o, 64);
    if (lane >= o) { Pp += tp; Pg += tg; }
  }

  // carry-in for the run containing my element 0
  const int nk0 = __shfl_down(k0, 1, 64);        // lanes 0..62 valid
  const bool uni = (k0 == k3);
  const bool cn  = uni && (k3 == nk0);           // continues into next lane
  const unsigned long long cmask = __ballot(cn);
  const unsigned long long below = (1ull << lane) - 1ull;
  const unsigned long long y = (~cmask) & below;
  const int L = y ? (64 - __clzll(y)) : 0;       // first lane of my carry range
  const int Lm1 = (L > 0) ? (L - 1) : 0;
  const float Ppm1 = __shfl_up(Pp, 1, 64);
  const float Pgm1 = __shfl_up(Pg, 1, 64);
  const float PpL = __shfl(Pp, Lm1, 64);
  const float PgL = __shfl(Pg, Lm1, 64);
  const int   k3L = __shfl(k3, Lm1, 64);
  const float tpL = __shfl(t3p, Lm1, 64);
  const float tgL = __shfl(t3g, Lm1, 64);
  float Cp = 0.f, Cg = 0.f;
  if (L < lane) {                                 // full uniform threads [L, lane-1]
    Cp = Ppm1 - (L > 0 ? PpL : 0.f);
    Cg = Pgm1 - (L > 0 ? PgL : 0.f);
  }
  if (L > 0 && k3L == k0) {                       // partial tail of thread L-1
    Cp += tpL; Cg += tgL;
  }
  const bool open = (y == 0);                     // run chains to wave start

  // rules j=0..2 (in-register neighbors)
  float gg0, sa0, gg1, sa1, gg2, sa2, gg3, sa3;
  rule_eval2(dp4.x, dp4.y, tk4.x, true, gg0, sa0);
  rule_eval2(dp4.y, dp4.z, tk4.y, true, gg1, sa1);
  rule_eval2(dp4.z, dp4.w, tk4.z, true, gg2, sa2);
  float dpn3 = __shfl_down(dp4.x, 1, 64);
  float ggn  = __shfl_down(gg0,  1, 64);

  // ---- LDS metadata ----
  if (lane == 0) { hk[wid] = k0; ndp0[wid] = dp4.x; ndp1[wid] = dp4.y; ntk[wid] = tk4.x; }
  if (is63) {
    twk[wid] = k3;
    twp[wid] = uni ? (Cp + Sp) : t3p;
    twg[wid] = uni ? (Cg + Sg) : t3g;
    wu_[wid] = (uni && open) ? 1 : 0;
  }
  if (tid == 0) { smeta[0] = k0; bnd[0] = 0.f; bnd[1] = 0.f; bnd[2] = 0.f; bnd[3] = 0.f; }
  if (tid == TPB - 1) smeta[1] = k3;
  __syncthreads();

  // cross-wave carry (wave-uniform walk, <=NW-1 steps)
  {
    const int myh = hk[wid];
    float Wp = 0.f, Wg = 0.f;
    for (int u = wid - 1; u >= 0; --u) {
      if (twk[u] != myh) break;
      Wp += twp[u]; Wg += twg[u];
      if (!wu_[u]) break;
    }
    if (open) { Cp += Wp; Cg += Wg; }
  }

  // lane-63 rule neighbor: LDS handoff from next wave (block-last: own loads)
  if (is63) {
    float a0, a1; int t0;
    if (tid == TPB - 1) { a0 = nb_dp; a1 = nb_dp1; t0 = nb_tk; }
    else                { a0 = ndp0[wid + 1]; a1 = ndp1[wid + 1]; t0 = ntk[wid + 1]; }
    float ng, ns_;
    rule_eval2(a0, a1, t0, base + EPT < Tn - 1, ng, ns_);
    dpn3 = a0; ggn = ng;
  }
  rule_eval2(dp4.w, dpn3, tk4.w, base + 3 < Tn - 1, gg3, sa3);

  // pdur + rules losses
  const float dpx[4] = {dp4.x, dp4.y, dp4.z, dp4.w};
  const float dgl[4] = {g0, g1_, g2_, g3_};
  const float sav[4] = {sa0, sa1, sa2, sa3};
  const float addv[4] = {gg1, gg2, gg3, (base + 3 < Tn - 1) ? ggn : 0.f};
  float pdur_s = 0.f, rules_s = 0.f;
  #pragma unroll
  for (int j = 0; j < 4; ++j) {
    float dp = dpx[j];
    float dr = dp - sav[j] + addv[j];
    float lp = __logf(dp + 1.f);
    float dlr = lp - __logf(dr + 1.f);
    rules_s += dlr * dlr;
    float dlg = lp - __logf(dgl[j] + 1.f);
    pdur_s += dlg * dlg;
  }

  // run-compress with carry; owner thread finalizes each completed word
  const int wf = smeta[0], wl = smeta[1];
  const int nk_true = is63 ? ((tid == TPB - 1) ? -1 : hk[wid + 1]) : nk0;
  float wd_s = 0.f;
  {
    const int   kk[4] = {k0, k1, k2, k3};
    const float pp[4] = {p0, p1, p2, p3};
    const float gg[4] = {g0, g1_, g2_, g3_};
    int cur = k0; float ap = Cp, ag = Cg;
    #pragma unroll
    for (int j = 0; j < 4; ++j) {
      if (kk[j] != cur) {
        if (cur == wl)      { bnd[2] = ap; bnd[3] = ag; }   // unique writer
        else if (cur == wf) { bnd[0] = ap; bnd[1] = ag; }   // unique writer
        else { float d = __logf(ap + 1.f) - __logf(ag + 1.f); wd_s += d * d; }
        cur = kk[j]; ap = 0.f; ag = 0.f;
      }
      ap += pp[j]; ag += gg[j];
    }
    if (nk_true != cur) {            // run ends at my last element -> I own it
      if (cur == wl)      { bnd[2] = ap; bnd[3] = ag; }
      else if (cur == wf) { bnd[0] = ap; bnd[1] = ag; }
      else { float d = __logf(ap + 1.f) - __logf(ag + 1.f); wd_s += d * d; }
    }
  }

  // single weighted reduction (sp/sg free: lane-63 inclusive prefix values)
  float x = 0.6f * pdur_s + 0.3f * rules_s + WDC * wd_s;
  x = wave_reduce(x);
  if (lane == 0) red[wid][0] = x;
  if (is63) { red[wid][1] = Pp; red[wid][2] = Pg; }
  __syncthreads();

  if (tid == 0) {
    float xs = 0.f, sp = 0.f, sg = 0.f;
    #pragma unroll
    for (int w = 0; w < NW; ++w) { xs += red[w][0]; sp += red[w][1]; sg += red[w][2]; }
    float4 a, b, c;
    a.x = xs; a.y = sp; a.z = sg; a.w = 0.f;
    const bool single = (wf == wl);
    b.x = bnd[0]; b.y = bnd[1]; b.z = __int_as_float(single ? -1 : wf); b.w = 0.f;
    c.x = bnd[2]; c.y = bnd[3]; c.z = __int_as_float(wl); c.w = 0.f;
    const size_t idx = (size_t)blockIdx.x * 3;
    partials[idx]     = a;
    partials[idx + 1] = b;
    partials[idx + 2] = c;
  }
}

// One block: thread r folds row r's BPR partials. All 12 float4 loads are
// hoisted ABOVE the merge chain so they issue independently (merge carries a
// serial dependence; loads must not).
__global__ __launch_bounds__(1024) void finalize_kernel(
    const float4* __restrict__ partials, float* __restrict__ out)
{
  __shared__ double wsum[16];
  const int r = threadIdx.x;            // one row per thread
  float4 A[BPR], Bv[BPR], Cv[BPR];
  #pragma unroll
  for (int j = 0; j < BPR; ++j) {
    const size_t idx = ((size_t)r * BPR + j) * 3;
    A[j]  = partials[idx];
    Bv[j] = partials[idx + 1];
    Cv[j] = partials[idx + 2];
  }

  double xs = 0.0, wdb = 0.0;
  float sp = 0.f, sg = 0.f;
  int curid = -1; float cp = 0.f, cg = 0.f;
  #pragma unroll
  for (int j = 0; j < BPR; ++j) {
    xs += (double)A[j].x; sp += A[j].y; sg += A[j].z;
    const int wfi = __float_as_int(Bv[j].z);
    const int wla = __float_as_int(Cv[j].z);
    if (wfi >= 0) {
      if (wfi != curid) {
        if (curid > 0) { float d = __logf(cp + 1.f) - __logf(cg + 1.f); wdb += (double)(d * d); }
        curid = wfi; cp = 0.f; cg = 0.f;
      }
      cp += Bv[j].x; cg += Bv[j].y;
    }
    if (wla >= 0) {
      if (wla != curid) {
        if (curid > 0) { float d = __logf(cp + 1.f) - __logf(cg + 1.f); wdb += (double)(d * d); }
        curid = wla; cp = 0.f; cg = 0.f;
      }
      cp += Cv[j].x; cg += Cv[j].y;
    }
  }
  if (curid > 0) { float d = __logf(cp + 1.f) - __logf(cg + 1.f); wdb += (double)(d * d); }

  float ds = __logf(sp + 1.f) - __logf(sg + 1.f);
  double contrib = xs / ((double)Bn * (double)Tn)
                 + 0.3 * wdb / ((double)Bn * (double)(Wn - 1))
                 + 0.1 * (double)(ds * ds) / (double)Bn;

  #pragma unroll
  for (int o = 32; o > 0; o >>= 1) contrib += __shfl_down(contrib, o, 64);
  if ((threadIdx.x & 63) == 0) wsum[threadIdx.x >> 6] = contrib;
  __syncthreads();
  if (threadIdx.x == 0) {
    double t = 0.0;
    #pragma unroll
    for (int i = 0; i < 16; ++i) t += wsum[i];
    out[0] = (float)t;
  }
}

extern "C" void kernel_launch(void* const* d_in, const int* in_sizes, int n_in,
                              void* d_out, int out_size, void* d_ws, size_t ws_size,
                              hipStream_t stream) {
  const float* dur_pred = (const float*)d_in[0];
  const float* dur_gt   = (const float*)d_in[1];
  const int*   ph2word  = (const int*)d_in[2];
  const int*   txt      = (const int*)d_in[3];

  // workspace: 4096 blocks x 48 B = 192 KB, fully overwritten (no memset)
  float4* partials = (float4*)d_ws;

  loss_kernel<<<Bn * BPR, TPB, 0, stream>>>(dur_pred, dur_gt, ph2word, txt, partials);
  finalize_kernel<<<1, 1024, 0, stream>>>(partials, (float*)d_out);
}

// Round 12
// 152.869 us; speedup vs baseline: 3.1378x; 1.0153x over previous
//
#include <hip/hip_runtime.h>

constexpr int Bn  = 1024;
constexpr int Tn  = 8192;
constexpr int Wn  = 2048;   // NUM_WORDS
constexpr int TPB = 512;
constexpr int NW  = TPB / 64;         // 8 waves per block
constexpr int EPT = 4;                // elements per thread
constexpr int SEG = TPB * EPT;        // 2048 elements per block
constexpr int BPR = Tn / SEG;         // 4 blocks per row
static_assert(BPR == 4, "blockIdx decode uses >>2 / &3");
// All loss terms are (log-difference)^2. We compute diffs in log2 and fold
// ln(2)^2 into the weights:  (ln a - ln b)^2 == LN2S * (log2 a - log2 b)^2.
constexpr float LN2S = 0.4804530139182014f;   // ln(2)^2
// fold wd into the per-block weighted scalar: 0.3*wd/(Bn*(Wn-1)) == WDC*wd/(Bn*Tn)
constexpr float WDC = 0.3f * (float)Tn / (float)(Wn - 1);

// Lean rule evaluation (algebraically identical to the reference; see R11).
__device__ __forceinline__ void rule_eval2(float dp, float dpn, int tok, bool valid_next,
                                           float& gg, float& sa) {
  const bool t27 = (tok == 27), t43 = (tok == 43);
  const bool in_init = (tok == 94) | (tok == 122) | (tok == 100) | (tok == 92) | t43 | t27;
  const float expected = (tok == 122) ? 3.f : ((t43 | t27) ? 5.f : 2.f);
  const float t1 = dp - expected;
  const bool fire1 = in_init && (t1 > 0.f);
  const float g1 = fire1 ? t1 : 0.f;
  const bool in_ratio = (tok == 44) | (tok == 28) | (tok == 29) | t27 | (tok == 121) | t43;
  const bool fire2 = in_ratio && valid_next && (3.f * dp > dpn);
  const float g2 = fire2 ? (dp - dpn * (1.f / 3.f)) : 0.f;
  gg = g1 + g2;
  sa = fire2 ? g2 : g1;
}

__device__ __forceinline__ float wave_reduce(float v) {
  #pragma unroll
  for (int o = 32; o > 0; o >>= 1) v += __shfl_down(v, o, 64);
  return v;
}

// R11 structure; only change: __logf -> __log2f (v_log_f32 without the ln2
// multiply), with LN2S folded into the weights.
__global__ __launch_bounds__(TPB, 4) void loss_kernel(
    const float* __restrict__ dur_pred, const float* __restrict__ dur_gt,
    const int* __restrict__ ph2word, const int* __restrict__ txt,
    float4* __restrict__ partials)
{
  __shared__ int   hk[NW];                 // head key (k0 of lane 0) per wave
  __shared__ float ndp0[NW], ndp1[NW];     // lane0's dp4.x/.y  (rule neighbor handoff)
  __shared__ int   ntk[NW];                // lane0's tk4.x
  __shared__ int   twk[NW];                // wave tail-run key
  __shared__ float twp[NW], twg[NW];       // wave tail-run in-wave sums
  __shared__ int   wu_[NW];                // wave is entirely one open run
  __shared__ float bnd[4];                 // {wf_p, wf_g, wl_p, wl_g}
  __shared__ int   smeta[2];               // {wf, wl}
  __shared__ float red[NW][3];             // {x, sp_wave, sg_wave}

  const int row = blockIdx.x >> 2;
  const int sub = blockIdx.x & 3;
  const int s = sub * SEG;
  const size_t roff = (size_t)row * Tn;
  const float* __restrict__ dpr = dur_pred + roff;
  const float* __restrict__ dgr = dur_gt + roff;
  const int*   __restrict__ pwr = ph2word + roff;
  const int*   __restrict__ tkr = txt + roff;

  const int tid  = threadIdx.x;
  const int lane = tid & 63;
  const int wid  = tid >> 6;
  const bool is63 = (lane == 63);
  const int base = s + tid * EPT;

  // ---- load phase ----
  float4 dp4 = *reinterpret_cast<const float4*>(dpr + base);
  float4 dg4 = *reinterpret_cast<const float4*>(dgr + base);
  int4   pw4 = *reinterpret_cast<const int4*>(pwr + base);
  int4   tk4 = *reinterpret_cast<const int4*>(tkr + base);

  // block-last thread: rule-neighbor comes from the next block's region
  float nb_dp = 0.f, nb_dp1 = 0.f; int nb_tk = -1;
  if (tid == TPB - 1) {
    const int p = base + EPT;
    if (p < Tn) { nb_dp = dpr[p]; nb_dp1 = dpr[p + 1]; nb_tk = tkr[p]; }
  }

  const int k0 = pw4.x, k1 = pw4.y, k2 = pw4.z, k3 = pw4.w;
  const float p0 = fmaxf(dp4.x, 0.f), p1 = fmaxf(dp4.y, 0.f),
              p2 = fmaxf(dp4.z, 0.f), p3 = fmaxf(dp4.w, 0.f);
  const float g0 = dg4.x, g1_ = dg4.y, g2_ = dg4.z, g3_ = dg4.w;
  const float Sp = p0 + p1 + p2 + p3;
  const float Sg = g0 + g1_ + g2_ + g3_;

  // trailing-run partial sums within this thread (elements with key == k3)
  float t3p = p3, t3g = g3_;
  if (k2 == k3) { t3p += p2; t3g += g2_;
    if (k1 == k3) { t3p += p1; t3g += g1_;
      if (k0 == k3) { t3p += p0; t3g += g0; } } }

  // inclusive prefix scans of full-thread sums (lane63 -> wave sp/sg for free)
  float Pp = Sp, Pg = Sg;
  #pragma unroll
  for (int o = 1; o < 64; o <<= 1) {
    float tp = __shfl_up(Pp, o, 64);
    float tg = __shfl_up(Pg, o, 64);
    if (lane >= o) { Pp += tp; Pg += tg; }
  }

  // carry-in for the run containing my element 0
  const int nk0 = __shfl_down(k0, 1, 64);        // lanes 0..62 valid
  const bool uni = (k0 == k3);
  const bool cn  = uni && (k3 == nk0);           // continues into next lane
  const unsigned long long cmask = __ballot(cn);
  const unsigned long long below = (1ull << lane) - 1ull;
  const unsigned long long y = (~cmask) & below;
  const int L = y ? (64 - __clzll(y)) : 0;       // first lane of my carry range
  const int Lm1 = (L > 0) ? (L - 1) : 0;
  const float Ppm1 = __shfl_up(Pp, 1, 64);
  const float Pgm1 = __shfl_up(Pg, 1, 64);
  const float PpL = __shfl(Pp, Lm1, 64);
  const float PgL = __shfl(Pg, Lm1, 64);
  const int   k3L = __shfl(k3, Lm1, 64);
  const float tpL = __shfl(t3p, Lm1, 64);
  const float tgL = __shfl(t3g, Lm1, 64);
  float Cp = 0.f, Cg = 0.f;
  if (L < lane) {                                 // full uniform threads [L, lane-1]
    Cp = Ppm1 - (L > 0 ? PpL : 0.f);
    Cg = Pgm1 - (L > 0 ? PgL : 0.f);
  }
  if (L > 0 && k3L == k0) {                       // partial tail of thread L-1
    Cp += tpL; Cg += tgL;
  }
  const bool open = (y == 0);                     // run chains to wave start

  // rules j=0..2 (in-register neighbors)
  float gg0, sa0, gg1, sa1, gg2, sa2, gg3, sa3;
  rule_eval2(dp4.x, dp4.y, tk4.x, true, gg0, sa0);
  rule_eval2(dp4.y, dp4.z, tk4.y, true, gg1, sa1);
  rule_eval2(dp4.z, dp4.w, tk4.z, true, gg2, sa2);
  float dpn3 = __shfl_down(dp4.x, 1, 64);
  float ggn  = __shfl_down(gg0,  1, 64);

  // ---- LDS metadata ----
  if (lane == 0) { hk[wid] = k0; ndp0[wid] = dp4.x; ndp1[wid] = dp4.y; ntk[wid] = tk4.x; }
  if (is63) {
    twk[wid] = k3;
    twp[wid] = uni ? (Cp + Sp) : t3p;
    twg[wid] = uni ? (Cg + Sg) : t3g;
    wu_[wid] = (uni && open) ? 1 : 0;
  }
  if (tid == 0) { smeta[0] = k0; bnd[0] = 0.f; bnd[1] = 0.f; bnd[2] = 0.f; bnd[3] = 0.f; }
  if (tid == TPB - 1) smeta[1] = k3;
  __syncthreads();

  // cross-wave carry (wave-uniform walk, <=NW-1 steps)
  {
    const int myh = hk[wid];
    float Wp = 0.f, Wg = 0.f;
    for (int u = wid - 1; u >= 0; --u) {
      if (twk[u] != myh) break;
      Wp += twp[u]; Wg += twg[u];
      if (!wu_[u]) break;
    }
    if (open) { Cp += Wp; Cg += Wg; }
  }

  // lane-63 rule neighbor: LDS handoff from next wave (block-last: own loads)
  if (is63) {
    float a0, a1; int t0;
    if (tid == TPB - 1) { a0 = nb_dp; a1 = nb_dp1; t0 = nb_tk; }
    else                { a0 = ndp0[wid + 1]; a1 = ndp1[wid + 1]; t0 = ntk[wid + 1]; }
    float ng, ns_;
    rule_eval2(a0, a1, t0, base + EPT < Tn - 1, ng, ns_);
    dpn3 = a0; ggn = ng;
  }
  rule_eval2(dp4.w, dpn3, tk4.w, base + 3 < Tn - 1, gg3, sa3);

  // pdur + rules losses (log2-space; LN2S folded into weights below)
  const float dpx[4] = {dp4.x, dp4.y, dp4.z, dp4.w};
  const float dgl[4] = {g0, g1_, g2_, g3_};
  const float sav[4] = {sa0, sa1, sa2, sa3};
  const float addv[4] = {gg1, gg2, gg3, (base + 3 < Tn - 1) ? ggn : 0.f};
  float pdur_s = 0.f, rules_s = 0.f;
  #pragma unroll
  for (int j = 0; j < 4; ++j) {
    float dp = dpx[j];
    float dr = dp - sav[j] + addv[j];
    float lp = __log2f(dp + 1.f);
    float dlr = lp - __log2f(dr + 1.f);
    rules_s += dlr * dlr;
    float dlg = lp - __log2f(dgl[j] + 1.f);
    pdur_s += dlg * dlg;
  }

  // run-compress with carry; owner thread finalizes each completed word
  const int wf = smeta[0], wl = smeta[1];
  const int nk_true = is63 ? ((tid == TPB - 1) ? -1 : hk[wid + 1]) : nk0;
  float wd_s = 0.f;
  {
    const int   kk[4] = {k0, k1, k2, k3};
    const float pp[4] = {p0, p1, p2, p3};
    const float gg[4] = {g0, g1_, g2_, g3_};
    int cur = k0; float ap = Cp, ag = Cg;
    #pragma unroll
    for (int j = 0; j < 4; ++j) {
      if (kk[j] != cur) {
        if (cur == wl)      { bnd[2] = ap; bnd[3] = ag; }   // unique writer
        else if (cur == wf) { bnd[0] = ap; bnd[1] = ag; }   // unique writer
        else { float d = __log2f(ap + 1.f) - __log2f(ag + 1.f); wd_s += d * d; }
        cur = kk[j]; ap = 0.f; ag = 0.f;
      }
      ap += pp[j]; ag += gg[j];
    }
    if (nk_true != cur) {            // run ends at my last element -> I own it
      if (cur == wl)      { bnd[2] = ap; bnd[3] = ag; }
      else if (cur == wf) { bnd[0] = ap; bnd[1] = ag; }
      else { float d = __log2f(ap + 1.f) - __log2f(ag + 1.f); wd_s += d * d; }
    }
  }

  // single weighted reduction (weights carry the ln2^2 factor)
  float x = (0.6f * LN2S) * pdur_s + (0.3f * LN2S) * rules_s + (WDC * LN2S) * wd_s;
  x = wave_reduce(x);
  if (lane == 0) red[wid][0] = x;
  if (is63) { red[wid][1] = Pp; red[wid][2] = Pg; }
  __syncthreads();

  if (tid == 0) {
    float xs = 0.f, sp = 0.f, sg = 0.f;
    #pragma unroll
    for (int w = 0; w < NW; ++w) { xs += red[w][0]; sp += red[w][1]; sg += red[w][2]; }
    float4 a, b, c;
    a.x = xs; a.y = sp; a.z = sg; a.w = 0.f;
    const bool single = (wf == wl);
    b.x = bnd[0]; b.y = bnd[1]; b.z = __int_as_float(single ? -1 : wf); b.w = 0.f;
    c.x = bnd[2]; c.y = bnd[3]; c.z = __int_as_float(wl); c.w = 0.f;
    const size_t idx = (size_t)blockIdx.x * 3;
    partials[idx]     = a;
    partials[idx + 1] = b;
    partials[idx + 2] = c;
  }
}

// One block: thread r folds row r's BPR partials (loads hoisted above the
// serial merge chain). log2-space diffs scaled by LN2S.
__global__ __launch_bounds__(1024) void finalize_kernel(
    const float4* __restrict__ partials, float* __restrict__ out)
{
  __shared__ double wsum[16];
  const int r = threadIdx.x;            // one row per thread
  float4 A[BPR], Bv[BPR], Cv[BPR];
  #pragma unroll
  for (int j = 0; j < BPR; ++j) {
    const size_t idx = ((size_t)r * BPR + j) * 3;
    A[j]  = partials[idx];
    Bv[j] = partials[idx + 1];
    Cv[j] = partials[idx + 2];
  }

  double xs = 0.0, wdb = 0.0;
  float sp = 0.f, sg = 0.f;
  int curid = -1; float cp = 0.f, cg = 0.f;
  #pragma unroll
  for (int j = 0; j < BPR; ++j) {
    xs += (double)A[j].x; sp += A[j].y; sg += A[j].z;
    const int wfi = __float_as_int(Bv[j].z);
    const int wla = __float_as_int(Cv[j].z);
    if (wfi >= 0) {
      if (wfi != curid) {
        if (curid > 0) { float d = __log2f(cp + 1.f) - __log2f(cg + 1.f); wdb += (double)(d * d); }
        curid = wfi; cp = 0.f; cg = 0.f;
      }
      cp += Bv[j].x; cg += Bv[j].y;
    }
    if (wla >= 0) {
      if (wla != curid) {
        if (curid > 0) { float d = __log2f(cp + 1.f) - __log2f(cg + 1.f); wdb += (double)(d * d); }
        curid = wla; cp = 0.f; cg = 0.f;
      }
      cp += Cv[j].x; cg += Cv[j].y;
    }
  }
  if (curid > 0) { float d = __log2f(cp + 1.f) - __log2f(cg + 1.f); wdb += (double)(d * d); }

  float ds = __log2f(sp + 1.f) - __log2f(sg + 1.f);
  double contrib = xs / ((double)Bn * (double)Tn)
                 + (0.3 * (double)LN2S) * wdb / ((double)Bn * (double)(Wn - 1))
                 + (0.1 * (double)LN2S) * (double)(ds * ds) / (double)Bn;

  #pragma unroll
  for (int o = 32; o > 0; o >>= 1) contrib += __shfl_down(contrib, o, 64);
  if ((threadIdx.x & 63) == 0) wsum[threadIdx.x >> 6] = contrib;
  __syncthreads();
  if (threadIdx.x == 0) {
    double t = 0.0;
    #pragma unroll
    for (int i = 0; i < 16; ++i) t += wsum[i];
    out[0] = (float)t;
  }
}

extern "C" void kernel_launch(void* const* d_in, const int* in_sizes, int n_in,
                              void* d_out, int out_size, void* d_ws, size_t ws_size,
                              hipStream_t stream) {
  const float* dur_pred = (const float*)d_in[0];
  const float* dur_gt   = (const float*)d_in[1];
  const int*   ph2word  = (const int*)d_in[2];
  const int*   txt      = (const int*)d_in[3];

  // workspace: 4096 blocks x 48 B = 192 KB, fully overwritten (no memset)
  float4* partials = (float4*)d_ws;

  loss_kernel<<<Bn * BPR, TPB, 0, stream>>>(dur_pred, dur_gt, ph2word, txt, partials);
  finalize_kernel<<<1, 1024, 0, stream>>>(partials, (float*)d_out);
}